// Round 6
// baseline (192.309 us; speedup 1.0000x reference)
//
#include <hip/hip_runtime.h>

#define K_TAPS 9
#define CC 64
#define HH 256
#define WW 256
#define BB 4
#define NN 16384
#define NPTS (BB * NN)
#define SCLX (2.0f / 255.0f)
#define SCLY (2.0f / 255.0f)
#define PRM_STRIDE 32

__device__ __forceinline__ float softplus_f(float x) {
    return fmaxf(x, 0.0f) + log1pf(expf(-fabsf(x)));
}
__device__ __forceinline__ float leaky_f(float x) { return x >= 0.0f ? x : 0.2f * x; }
__device__ __forceinline__ float clampf(float x, float lo, float hi) {
    return fminf(fmaxf(x, lo), hi);
}

// transpose (B, C, H*W) -> (B, H*W, C)
__global__ void __launch_bounds__(256) transpose_kernel(const float* __restrict__ feat,
                                                        float* __restrict__ featT) {
    __shared__ float tile[64][65];
    int b = blockIdx.y;
    int p0 = blockIdx.x * 64;
    int tp = threadIdx.x & 63;
    int tq = threadIdx.x >> 6;
    const float* fb = feat + (size_t)b * CC * HH * WW;
#pragma unroll
    for (int i = 0; i < 16; ++i) {
        int c = tq * 16 + i;
        tile[c][tp] = fb[(size_t)c * (HH * WW) + p0 + tp];
    }
    __syncthreads();
    float* ob = featT + ((size_t)b * (HH * WW) + p0) * CC;
#pragma unroll
    for (int i = 0; i < 16; ++i) {
        int p = tq * 16 + i;
        ob[(size_t)p * CC + tp] = tile[tp][p];
    }
}

// bilinear sample of 4 channels (one float4) at grid coords (gx,gy) in [-1,1]
__device__ __forceinline__ float4 bilin4(const float4* __restrict__ base, float gx, float gy,
                                         int c4) {
    float ix = clampf((gx + 1.0f) * 0.5f * 255.0f, 0.0f, 255.0f);
    float iy = clampf((gy + 1.0f) * 0.5f * 255.0f, 0.0f, 255.0f);
    float x0f = floorf(ix), y0f = floorf(iy);
    float wx = ix - x0f, wy = iy - y0f;
    int x0 = (int)x0f, y0 = (int)y0f;
    int x1 = min(x0 + 1, 255), y1 = min(y0 + 1, 255);
    float4 f00 = base[((y0 << 8) + x0) * 16 + c4];
    float4 f01 = base[((y0 << 8) + x1) * 16 + c4];
    float4 f10 = base[((y1 << 8) + x0) * 16 + c4];
    float4 f11 = base[((y1 << 8) + x1) * 16 + c4];
    float omx = 1.0f - wx, omy = 1.0f - wy;
    float4 v;
    v.x = (f00.x * omx + f01.x * wx) * omy + (f10.x * omx + f11.x * wx) * wy;
    v.y = (f00.y * omx + f01.y * wx) * omy + (f10.y * omx + f11.y * wx) * wy;
    v.z = (f00.z * omx + f01.z * wx) * omy + (f10.z * omx + f11.z * wx) * wy;
    v.w = (f00.w * omx + f01.w * wx) * omy + (f10.w * omx + f11.w * wx) * wy;
    return v;
}

// ---------------- K2: MLP with wave-uniform (scalar) weight streaming ----------------
// 64 points/block, 256 threads. thread = (pt = t&63, quarter = t>>6).
// quarter is the wave index -> all weight addresses are wave-uniform -> s_load (SMEM pipe).
// Each thread computes 16 of 64 hidden units for its point; activations bounce through
// LDS with row-uniform, lane-consecutive access (conflict-free). Double buffer avoids
// read/write hazards with one barrier per transition.
__global__ void __launch_bounds__(256) mlp_kernel(const float4* __restrict__ ft4,
                                                  const float* __restrict__ coords,
                                                  const float* __restrict__ cell,
                                                  const float* __restrict__ W1,
                                                  const float* __restrict__ b1,
                                                  const float* __restrict__ Wr,
                                                  const float* __restrict__ br,
                                                  const float* __restrict__ W2,
                                                  const float* __restrict__ b2,
                                                  float* __restrict__ prm) {
    __shared__ float bufA[68][66];  // input feats + coords/cell; later h2; rows uniform per instr
    __shared__ float bufB[64][66];  // h; later layer-3 outputs (29 rows)

    const int t = threadIdx.x;
    const int pt = t & 63;
    const int quarter = t >> 6;  // == wave id, uniform per wave
    const int blk0 = blockIdx.x * 64;
    const int pg = blk0 + pt;
    const int bb = pg >> 14;
    const float gx = coords[2 * pg], gy = coords[2 * pg + 1];

    // ---- Phase A: anchor bilinear gather. thread covers quads qq = quarter + 4g ----
    {
        float ix = clampf((gx + 1.0f) * 0.5f * 255.0f, 0.0f, 255.0f);
        float iy = clampf((gy + 1.0f) * 0.5f * 255.0f, 0.0f, 255.0f);
        float x0f = floorf(ix), y0f = floorf(iy);
        float wx = ix - x0f, wy = iy - y0f;
        int x0 = (int)x0f, y0 = (int)y0f;
        int x1 = min(x0 + 1, 255), y1 = min(y0 + 1, 255);
        const float4* base = ft4 + (size_t)bb * (HH * WW) * 16;
        int i00 = ((y0 << 8) + x0) * 16, i01 = ((y0 << 8) + x1) * 16;
        int i10 = ((y1 << 8) + x0) * 16, i11 = ((y1 << 8) + x1) * 16;
        float w00 = (1.0f - wx) * (1.0f - wy), w01 = wx * (1.0f - wy);
        float w10 = (1.0f - wx) * wy, w11 = wx * wy;
#pragma unroll
        for (int g = 0; g < 4; ++g) {
            int qq = quarter + 4 * g;  // wave-uniform row group
            float4 f00 = base[i00 + qq], f01 = base[i01 + qq];
            float4 f10 = base[i10 + qq], f11 = base[i11 + qq];
            bufA[4 * qq + 0][pt] = f00.x * w00 + f01.x * w01 + f10.x * w10 + f11.x * w11;
            bufA[4 * qq + 1][pt] = f00.y * w00 + f01.y * w01 + f10.y * w10 + f11.y * w11;
            bufA[4 * qq + 2][pt] = f00.z * w00 + f01.z * w01 + f10.z * w10 + f11.z * w11;
            bufA[4 * qq + 3][pt] = f00.w * w00 + f01.w * w01 + f10.w * w10 + f11.w * w11;
        }
        if (quarter == 0) {
            bufA[64][pt] = gx;
            bufA[65][pt] = gy;
            bufA[66][pt] = cell[2 * pg];
            bufA[67][pt] = cell[2 * pg + 1];
        }
    }
    __syncthreads();

    const int j0 = 16 * quarter;

    // ---- Layer 1: h[j0..j0+15] = leaky(in @ W1 + b1) ----
    float h[16];
#pragma unroll
    for (int j = 0; j < 16; ++j) h[j] = b1[j0 + j];
#pragma unroll 4
    for (int i = 0; i < 68; ++i) {
        float a = bufA[i][pt];
#pragma unroll
        for (int j = 0; j < 16; ++j) h[j] = fmaf(a, W1[i * 64 + j0 + j], h[j]);
    }
#pragma unroll
    for (int j = 0; j < 16; ++j) {
        h[j] = leaky_f(h[j]);
        bufB[j0 + j][pt] = h[j];
    }
    __syncthreads();

    // ---- Layer 2: h2 = leaky(h + h @ Wr + br) ----
    float h2[16];
#pragma unroll
    for (int j = 0; j < 16; ++j) h2[j] = br[j0 + j];
#pragma unroll 4
    for (int i = 0; i < 64; ++i) {
        float a = bufB[i][pt];
#pragma unroll
        for (int j = 0; j < 16; ++j) h2[j] = fmaf(a, Wr[i * 64 + j0 + j], h2[j]);
    }
#pragma unroll
    for (int j = 0; j < 16; ++j) {
        h2[j] = leaky_f(h[j] + h2[j]);
        bufA[j0 + j][pt] = h2[j];  // overwrite input rows; all L1 reads completed at barrier
    }
    __syncthreads();

    // ---- Layer 3: out = h2 @ W2 + b2; quarter handles j = 8q..8q+7 (29 valid) ----
    {
        const int jb = 8 * quarter;
        float o[8];
#pragma unroll
        for (int jo = 0; jo < 8; ++jo) o[jo] = (jb + jo < 29) ? b2[jb + jo] : 0.0f;
#pragma unroll 4
        for (int i = 0; i < 64; ++i) {
            float a = bufA[i][pt];
#pragma unroll
            for (int jo = 0; jo < 8; ++jo)
                if (jb + jo < 29) o[jo] = fmaf(a, W2[i * 29 + jb + jo], o[jo]);
        }
#pragma unroll
        for (int jo = 0; jo < 8; ++jo)
            if (jb + jo < 29) bufB[jb + jo][pt] = o[jo];
    }
    __syncthreads();

    // ---- Head: duplicated per quarter; quarter writes taps k = quarter + 4*ii ----
    {
        float r = clampf(softplus_f(bufB[0][pt]) + 0.1f, 0.1f, 4.0f);
        float sg = clampf(softplus_f(bufB[1][pt]) + 0.5f, 0.5f, 6.0f);
        float se = sg * 2.0f;
        float inv2 = -0.5f / (se * se + 1e-8f);
        float sx[9], sy[9], wv[9];
        float s = 0.0f;
#pragma unroll
        for (int k = 0; k < K_TAPS; ++k) {
            float bx = (float)(k % 3 - 1);
            float by = (float)(k / 3 - 1);
            float ox = fmaf(r, bx, tanhf(bufB[2 + 2 * k][pt]) * 0.5f);
            float oy = fmaf(r, by, tanhf(bufB[3 + 2 * k][pt]) * 0.5f);
            float d2 = ox * ox + oy * oy;
            float wgeo = expf(d2 * inv2);
            float gate = 1.0f / (1.0f + expf(-bufB[20 + k][pt]));
            float w = wgeo * gate;
            wv[k] = w;
            s += w;
            sx[k] = fmaf(ox, SCLX, gx);
            sy[k] = fmaf(oy, SCLY, gy);
        }
        float inv = 1.0f / (s + 1e-8f);
        float* pp = prm + (size_t)pg * PRM_STRIDE;
#pragma unroll
        for (int ii = 0; ii < 3; ++ii) {
            int k = quarter + 4 * ii;
            if (k < K_TAPS) {
                pp[3 * k + 0] = sx[k];
                pp[3 * k + 1] = sy[k];
                pp[3 * k + 2] = wv[k] * inv;
            }
        }
    }
}

// ---------------- K3: deformable gather, thread = (point, channel-quad) ----------------
__global__ void __launch_bounds__(256) gather_kernel(const float4* __restrict__ ft4,
                                                     const float* __restrict__ prm,
                                                     float4* __restrict__ out4) {
    int tid = blockIdx.x * 256 + threadIdx.x;
    int c4 = tid & 15;
    int p = tid >> 4;
    int bb = p >> 14;
    const float4* base = ft4 + (size_t)bb * (HH * WW) * 16;
    const float* pp = prm + (size_t)p * PRM_STRIDE;
    float4 acc = make_float4(0.0f, 0.0f, 0.0f, 0.0f);
#pragma unroll 3
    for (int k = 0; k < K_TAPS; ++k) {
        float sx = pp[3 * k + 0];
        float sy = pp[3 * k + 1];
        float wk = pp[3 * k + 2];
        float4 v = bilin4(base, sx, sy, c4);
        acc.x = fmaf(v.x, wk, acc.x);
        acc.y = fmaf(v.y, wk, acc.y);
        acc.z = fmaf(v.z, wk, acc.z);
        acc.w = fmaf(v.w, wk, acc.w);
    }
    out4[(size_t)p * 16 + c4] = acc;
}

// ---------------- small fallback: CHW, wave per point (no workspace) ----------------
__device__ __forceinline__ float bilin_chw(const float* __restrict__ feat, int b, int lane,
                                           float gx, float gy) {
    float ix = clampf((gx + 1.0f) * 0.5f * 255.0f, 0.0f, 255.0f);
    float iy = clampf((gy + 1.0f) * 0.5f * 255.0f, 0.0f, 255.0f);
    float x0f = floorf(ix), y0f = floorf(iy);
    float wx = ix - x0f, wy = iy - y0f;
    int x0 = (int)x0f, y0 = (int)y0f;
    int x1 = min(x0 + 1, 255), y1 = min(y0 + 1, 255);
    const float* base = feat + ((size_t)b * CC + lane) * (HH * WW);
    float f00 = base[(y0 << 8) + x0];
    float f01 = base[(y0 << 8) + x1];
    float f10 = base[(y1 << 8) + x0];
    float f11 = base[(y1 << 8) + x1];
    float omx = 1.0f - wx, omy = 1.0f - wy;
    return (f00 * omx + f01 * wx) * omy + (f10 * omx + f11 * wx) * wy;
}

__global__ void __launch_bounds__(256) fallback_kernel(const float* __restrict__ feat,
                                                       const float* __restrict__ coords,
                                                       const float* __restrict__ cell,
                                                       const float* __restrict__ W1,
                                                       const float* __restrict__ b1,
                                                       const float* __restrict__ Wr,
                                                       const float* __restrict__ br,
                                                       const float* __restrict__ W2,
                                                       const float* __restrict__ b2,
                                                       float* __restrict__ out) {
    int lane = threadIdx.x & 63;
    int wave = threadIdx.x >> 6;
    int pidx = blockIdx.x * 4 + wave;
    if (pidx >= NPTS) return;
    int b = pidx >> 14;
    float gx = coords[(size_t)pidx * 2 + 0];
    float gy = coords[(size_t)pidx * 2 + 1];
    float cx = cell[(size_t)pidx * 2 + 0];
    float cy = cell[(size_t)pidx * 2 + 1];
    float fa = bilin_chw(feat, b, lane, gx, gy);
    float h = b1[lane];
#pragma unroll
    for (int i = 0; i < 64; ++i) {
        float a = __shfl(fa, i, 64);
        h = fmaf(a, W1[i * 64 + lane], h);
    }
    h = fmaf(gx, W1[64 * 64 + lane], h);
    h = fmaf(gy, W1[65 * 64 + lane], h);
    h = fmaf(cx, W1[66 * 64 + lane], h);
    h = fmaf(cy, W1[67 * 64 + lane], h);
    h = leaky_f(h);
    float h2 = br[lane];
#pragma unroll
    for (int i = 0; i < 64; ++i) {
        float a = __shfl(h, i, 64);
        h2 = fmaf(a, Wr[i * 64 + lane], h2);
    }
    h2 = leaky_f(h + h2);
    int j = lane < 29 ? lane : 0;
    float o = b2[j];
#pragma unroll
    for (int i = 0; i < 64; ++i) {
        float a = __shfl(h2, i, 64);
        o = fmaf(a, W2[i * 29 + j], o);
    }
    int kk = lane < K_TAPS ? lane : 0;
    float r_raw = __shfl(o, 0, 64);
    float s_raw = __shfl(o, 1, 64);
    float rx_raw = __shfl(o, 2 + 2 * kk, 64);
    float ry_raw = __shfl(o, 3 + 2 * kk, 64);
    float g_raw = __shfl(o, 20 + kk, 64);
    float r = clampf(softplus_f(r_raw) + 0.1f, 0.1f, 4.0f);
    float sg = clampf(softplus_f(s_raw) + 0.5f, 0.5f, 6.0f);
    float bx = (float)(kk % 3 - 1);
    float by = (float)(kk / 3 - 1);
    float offx = fmaf(r, bx, tanhf(rx_raw) * 0.5f);
    float offy = fmaf(r, by, tanhf(ry_raw) * 0.5f);
    float d2 = offx * offx + offy * offy;
    float se = sg * 2.0f;
    float wgeo = expf(-0.5f * d2 / (se * se + 1e-8f));
    float gate = 1.0f / (1.0f + expf(-g_raw));
    float w = wgeo * gate;
    float wv = (lane < K_TAPS) ? w : 0.0f;
#pragma unroll
    for (int m = 32; m >= 1; m >>= 1) wv += __shfl_xor(wv, m, 64);
    float wn = w / (wv + 1e-8f);
    float acc = 0.0f;
#pragma unroll
    for (int k = 0; k < K_TAPS; ++k) {
        float ox = __shfl(offx, k, 64) * SCLX;
        float oy = __shfl(offy, k, 64) * SCLY;
        float wk2 = __shfl(wn, k, 64);
        float fv = bilin_chw(feat, b, lane, gx + ox, gy + oy);
        acc = fmaf(fv, wk2, acc);
    }
    out[(size_t)pidx * CC + lane] = acc;
}

extern "C" void kernel_launch(void* const* d_in, const int* in_sizes, int n_in,
                              void* d_out, int out_size, void* d_ws, size_t ws_size,
                              hipStream_t stream) {
    const float* feat = (const float*)d_in[0];
    const float* coords = (const float*)d_in[1];
    const float* cell = (const float*)d_in[2];
    const float* W1 = (const float*)d_in[3];
    const float* b1 = (const float*)d_in[4];
    const float* Wr = (const float*)d_in[5];
    const float* br = (const float*)d_in[6];
    const float* W2 = (const float*)d_in[7];
    const float* b2 = (const float*)d_in[8];
    float* out = (float*)d_out;

    const size_t needT = (size_t)BB * HH * WW * CC * sizeof(float);  // 64 MB
    const size_t needP = (size_t)NPTS * PRM_STRIDE * sizeof(float);  // 8 MB

    if (ws_size >= needT + needP) {
        float* featT = (float*)d_ws;
        float* prm = (float*)((char*)d_ws + needT);
        dim3 tg((HH * WW) / 64, BB);
        transpose_kernel<<<tg, 256, 0, stream>>>(feat, featT);
        mlp_kernel<<<NPTS / 64, 256, 0, stream>>>((const float4*)featT, coords, cell, W1, b1,
                                                  Wr, br, W2, b2, prm);
        gather_kernel<<<(NPTS * 16) / 256, 256, 0, stream>>>((const float4*)featT, prm,
                                                             (float4*)out);
    } else {
        fallback_kernel<<<NPTS / 4, 256, 0, stream>>>(feat, coords, cell, W1, b1, Wr, br, W2,
                                                      b2, out);
    }
}

// Round 7
// 116.886 us; speedup vs baseline: 1.6453x; 1.6453x over previous
//
#include <hip/hip_runtime.h>

#define K_TAPS 9
#define CC 64
#define HH 256
#define WW 256
#define BB 4
#define NN 16384
#define NPTS (BB * NN)
#define SCLX (2.0f / 255.0f)
#define SCLY (2.0f / 255.0f)
#define PRM_STRIDE 32
#define AS 68  // act row stride (floats)

__device__ __forceinline__ float softplus_f(float x) {
    return fmaxf(x, 0.0f) + log1pf(expf(-fabsf(x)));
}
__device__ __forceinline__ float leaky_f(float x) { return x >= 0.0f ? x : 0.2f * x; }
__device__ __forceinline__ float clampf(float x, float lo, float hi) {
    return fminf(fmaxf(x, lo), hi);
}

// transpose (B, C, H*W) -> (B, H*W, C)
__global__ void __launch_bounds__(256) transpose_kernel(const float* __restrict__ feat,
                                                        float* __restrict__ featT) {
    __shared__ float tile[64][65];
    int b = blockIdx.y;
    int p0 = blockIdx.x * 64;
    int tp = threadIdx.x & 63;
    int tq = threadIdx.x >> 6;
    const float* fb = feat + (size_t)b * CC * HH * WW;
#pragma unroll
    for (int i = 0; i < 16; ++i) {
        int c = tq * 16 + i;
        tile[c][tp] = fb[(size_t)c * (HH * WW) + p0 + tp];
    }
    __syncthreads();
    float* ob = featT + ((size_t)b * (HH * WW) + p0) * CC;
#pragma unroll
    for (int i = 0; i < 16; ++i) {
        int p = tq * 16 + i;
        ob[(size_t)p * CC + tp] = tile[tp][p];
    }
}

// bilinear sample of 4 channels (one float4) at grid coords (gx,gy) in [-1,1]
__device__ __forceinline__ float4 bilin4(const float4* __restrict__ base, float gx, float gy,
                                         int c4) {
    float ix = clampf((gx + 1.0f) * 0.5f * 255.0f, 0.0f, 255.0f);
    float iy = clampf((gy + 1.0f) * 0.5f * 255.0f, 0.0f, 255.0f);
    float x0f = floorf(ix), y0f = floorf(iy);
    float wx = ix - x0f, wy = iy - y0f;
    int x0 = (int)x0f, y0 = (int)y0f;
    int x1 = min(x0 + 1, 255), y1 = min(y0 + 1, 255);
    float4 f00 = base[((y0 << 8) + x0) * 16 + c4];
    float4 f01 = base[((y0 << 8) + x1) * 16 + c4];
    float4 f10 = base[((y1 << 8) + x0) * 16 + c4];
    float4 f11 = base[((y1 << 8) + x1) * 16 + c4];
    float omx = 1.0f - wx, omy = 1.0f - wy;
    float4 v;
    v.x = (f00.x * omx + f01.x * wx) * omy + (f10.x * omx + f11.x * wx) * wy;
    v.y = (f00.y * omx + f01.y * wx) * omy + (f10.y * omx + f11.y * wx) * wy;
    v.z = (f00.z * omx + f01.z * wx) * omy + (f10.z * omx + f11.z * wx) * wy;
    v.w = (f00.w * omx + f01.w * wx) * omy + (f10.w * omx + f11.w * wx) * wy;
    return v;
}

// ---------------- K2: register-blocked MLP, 64 points/block, 4x4 tile/thread ----------------
// Weights staged in LDS (one reusable buffer per layer). Inner loop:
//   2 x ds_read_b128 (act quad + weight quad, both 2-way bank alias = free) + 16 FMA.
// thread t: q = t&15 (output j-quad), pgrp = t>>4 (point-quad).
__global__ void __launch_bounds__(256) mlp_kernel(const float4* __restrict__ ft4,
                                                  const float* __restrict__ coords,
                                                  const float* __restrict__ cell,
                                                  const float* __restrict__ W1,
                                                  const float* __restrict__ b1,
                                                  const float* __restrict__ Wr,
                                                  const float* __restrict__ br,
                                                  const float* __restrict__ W2,
                                                  const float* __restrict__ b2,
                                                  float* __restrict__ prm) {
    __shared__ __align__(16) float act[68 * AS];    // [feature i][point 0..63], stride 68
    __shared__ __align__(16) float wbuf[68 * 64];   // W1 -> Wr -> (W2 | sot)
    float4* wbuf4 = (float4*)wbuf;

    const int t = threadIdx.x;
    const int q = t & 15;
    const int pgrp = t >> 4;
    const int blk0 = blockIdx.x * 64;

    // ---- stage W1 into LDS (in flight across phase A) ----
    {
        const float4* w1g = (const float4*)W1;  // 68*64/4 = 1088 float4
#pragma unroll
        for (int idx = t; idx < 1088; idx += 256) wbuf4[idx] = w1g[idx];
    }

    // ---- Phase A: anchor bilinear gather. thread = point (t&63); wave covers quads ----
    {
        const int pt = t & 63;
        const int wvi = t >> 6;  // wave id 0..3
        const int pg = blk0 + pt;
        const int bb = pg >> 14;
        const float gx = coords[2 * pg], gy = coords[2 * pg + 1];
        float ix = clampf((gx + 1.0f) * 0.5f * 255.0f, 0.0f, 255.0f);
        float iy = clampf((gy + 1.0f) * 0.5f * 255.0f, 0.0f, 255.0f);
        float x0f = floorf(ix), y0f = floorf(iy);
        float wx = ix - x0f, wy = iy - y0f;
        int x0 = (int)x0f, y0 = (int)y0f;
        int x1 = min(x0 + 1, 255), y1 = min(y0 + 1, 255);
        const float4* base = ft4 + (size_t)bb * (HH * WW) * 16;
        int i00 = ((y0 << 8) + x0) * 16, i01 = ((y0 << 8) + x1) * 16;
        int i10 = ((y1 << 8) + x0) * 16, i11 = ((y1 << 8) + x1) * 16;
        float w00 = (1.0f - wx) * (1.0f - wy), w01 = wx * (1.0f - wy);
        float w10 = (1.0f - wx) * wy, w11 = wx * wy;
#pragma unroll
        for (int g = 0; g < 4; ++g) {
            int qq = 4 * g + wvi;  // wave-uniform quad -> stores hit consecutive banks via pt
            float4 f00 = base[i00 + qq], f01 = base[i01 + qq];
            float4 f10 = base[i10 + qq], f11 = base[i11 + qq];
            act[(4 * qq + 0) * AS + pt] = f00.x * w00 + f01.x * w01 + f10.x * w10 + f11.x * w11;
            act[(4 * qq + 1) * AS + pt] = f00.y * w00 + f01.y * w01 + f10.y * w10 + f11.y * w11;
            act[(4 * qq + 2) * AS + pt] = f00.z * w00 + f01.z * w01 + f10.z * w10 + f11.z * w11;
            act[(4 * qq + 3) * AS + pt] = f00.w * w00 + f01.w * w01 + f10.w * w10 + f11.w * w11;
        }
        if (wvi == 0) {
            act[64 * AS + pt] = gx;
            act[65 * AS + pt] = gy;
            act[66 * AS + pt] = cell[2 * pg];
            act[67 * AS + pt] = cell[2 * pg + 1];
        }
    }
    __syncthreads();

    // ---- Layer 1: h = leaky(in @ W1 + b1) ----
    float hres[4][4];
    {
        float acc[4][4];
        float4 b4 = ((const float4*)b1)[q];
        float bj[4] = {b4.x, b4.y, b4.z, b4.w};
#pragma unroll
        for (int j = 0; j < 4; ++j)
#pragma unroll
            for (int p = 0; p < 4; ++p) acc[j][p] = bj[j];
#pragma unroll 4
        for (int i = 0; i < 68; ++i) {
            float4 av = *(const float4*)&act[i * AS + 4 * pgrp];
            float4 wv4 = *(const float4*)&wbuf[i * 64 + 4 * q];
            float a[4] = {av.x, av.y, av.z, av.w};
            float wj[4] = {wv4.x, wv4.y, wv4.z, wv4.w};
#pragma unroll
            for (int j = 0; j < 4; ++j)
#pragma unroll
                for (int p = 0; p < 4; ++p) acc[j][p] = fmaf(a[p], wj[j], acc[j][p]);
        }
#pragma unroll
        for (int j = 0; j < 4; ++j)
#pragma unroll
            for (int p = 0; p < 4; ++p) hres[j][p] = leaky_f(acc[j][p]);
    }
    __syncthreads();  // layer-1 act & wbuf reads complete

    // write h into act rows; stage Wr
#pragma unroll
    for (int j = 0; j < 4; ++j)
        *(float4*)&act[(4 * q + j) * AS + 4 * pgrp] =
            make_float4(hres[j][0], hres[j][1], hres[j][2], hres[j][3]);
    {
        const float4* wrg = (const float4*)Wr;  // 1024 float4
#pragma unroll
        for (int idx = t; idx < 1024; idx += 256) wbuf4[idx] = wrg[idx];
    }
    __syncthreads();

    // ---- Layer 2: h2 = leaky(h + h @ Wr + br) ----
    float h2[4][4];
    {
        float4 b4 = ((const float4*)br)[q];
        float bj[4] = {b4.x, b4.y, b4.z, b4.w};
#pragma unroll
        for (int j = 0; j < 4; ++j)
#pragma unroll
            for (int p = 0; p < 4; ++p) h2[j][p] = bj[j];
#pragma unroll 4
        for (int i = 0; i < 64; ++i) {
            float4 av = *(const float4*)&act[i * AS + 4 * pgrp];
            float4 wv4 = *(const float4*)&wbuf[i * 64 + 4 * q];
            float a[4] = {av.x, av.y, av.z, av.w};
            float wj[4] = {wv4.x, wv4.y, wv4.z, wv4.w};
#pragma unroll
            for (int j = 0; j < 4; ++j)
#pragma unroll
                for (int p = 0; p < 4; ++p) h2[j][p] = fmaf(a[p], wj[j], h2[j][p]);
        }
#pragma unroll
        for (int j = 0; j < 4; ++j)
#pragma unroll
            for (int p = 0; p < 4; ++p) h2[j][p] = leaky_f(hres[j][p] + h2[j][p]);
    }
    __syncthreads();  // layer-2 reads complete

    // write h2 into act rows; stage W2 (64x29 = 1856 floats = 464 float4)
#pragma unroll
    for (int j = 0; j < 4; ++j)
        *(float4*)&act[(4 * q + j) * AS + 4 * pgrp] =
            make_float4(h2[j][0], h2[j][1], h2[j][2], h2[j][3]);
    {
        const float4* w2g = (const float4*)W2;
#pragma unroll
        for (int idx = t; idx < 464; idx += 256) wbuf4[idx] = w2g[idx];
    }
    __syncthreads();

    float* sot = wbuf + 2048;  // [64][30] overlay past W2's 1856 floats

    // ---- Layer 3: out = h2 @ W2 + b2; thread does j0=2q, j1=2q+1 for its 4 points ----
    {
        const int j0 = 2 * q, j1 = 2 * q + 1;
        const int jj0 = min(j0, 28), jj1 = min(j1, 28);
        float o0[4], o1[4];
        float bb0 = b2[jj0], bb1 = b2[jj1];
#pragma unroll
        for (int p = 0; p < 4; ++p) {
            o0[p] = bb0;
            o1[p] = bb1;
        }
#pragma unroll 4
        for (int i = 0; i < 64; ++i) {
            float4 av = *(const float4*)&act[i * AS + 4 * pgrp];
            float a[4] = {av.x, av.y, av.z, av.w};
            float w0 = wbuf[i * 29 + jj0], w1 = wbuf[i * 29 + jj1];
#pragma unroll
            for (int p = 0; p < 4; ++p) {
                o0[p] = fmaf(a[p], w0, o0[p]);
                o1[p] = fmaf(a[p], w1, o1[p]);
            }
        }
#pragma unroll
        for (int p = 0; p < 4; ++p) {
            int pt = 4 * pgrp + p;
            if (j0 < 29) sot[pt * 30 + j0] = o0[p];
            if (j1 < 29) sot[pt * 30 + j1] = o1[p];
        }
    }
    __syncthreads();

    // ---- Head: 4 threads/point; sub handles taps k = sub, sub+4, sub+8 ----
    {
        const int pt = t >> 2, sub = t & 3;
        const int pg = blk0 + pt;
        const float* so = sot + pt * 30;
        float gx = coords[2 * pg], gy = coords[2 * pg + 1];
        float r = clampf(softplus_f(so[0]) + 0.1f, 0.1f, 4.0f);
        float sg = clampf(softplus_f(so[1]) + 0.5f, 0.5f, 6.0f);
        float se = sg * 2.0f;
        float inv2 = -0.5f / (se * se + 1e-8f);
        float sx[3], sy[3], wv[3];
        float s = 0.0f;
#pragma unroll
        for (int ii = 0; ii < 3; ++ii) {
            int kr = 4 * ii + sub;
            int k = kr < 9 ? kr : 0;
            float bx = (float)(k % 3 - 1);
            float by = (float)(k / 3 - 1);
            float ox = fmaf(r, bx, tanhf(so[2 + 2 * k]) * 0.5f);
            float oy = fmaf(r, by, tanhf(so[3 + 2 * k]) * 0.5f);
            float d2 = ox * ox + oy * oy;
            float wgeo = expf(d2 * inv2);
            float gate = 1.0f / (1.0f + expf(-so[20 + k]));
            float w = (kr < 9) ? wgeo * gate : 0.0f;
            wv[ii] = w;
            s += w;
            sx[ii] = fmaf(ox, SCLX, gx);
            sy[ii] = fmaf(oy, SCLY, gy);
        }
        s += __shfl_xor(s, 1, 64);
        s += __shfl_xor(s, 2, 64);
        float inv = 1.0f / (s + 1e-8f);
        float* pp = prm + (size_t)pg * PRM_STRIDE;
#pragma unroll
        for (int ii = 0; ii < 3; ++ii) {
            int kr = 4 * ii + sub;
            if (kr < 9) {
                pp[3 * kr + 0] = sx[ii];
                pp[3 * kr + 1] = sy[ii];
                pp[3 * kr + 2] = wv[ii] * inv;
            }
        }
    }
}

// ---------------- K3: deformable gather, thread = (point, channel-quad) ----------------
__global__ void __launch_bounds__(256) gather_kernel(const float4* __restrict__ ft4,
                                                     const float* __restrict__ prm,
                                                     float4* __restrict__ out4) {
    int tid = blockIdx.x * 256 + threadIdx.x;
    int c4 = tid & 15;
    int p = tid >> 4;
    int bb = p >> 14;
    const float4* base = ft4 + (size_t)bb * (HH * WW) * 16;
    const float* pp = prm + (size_t)p * PRM_STRIDE;
    float4 acc = make_float4(0.0f, 0.0f, 0.0f, 0.0f);
#pragma unroll 3
    for (int k = 0; k < K_TAPS; ++k) {
        float sx = pp[3 * k + 0];
        float sy = pp[3 * k + 1];
        float wk = pp[3 * k + 2];
        float4 v = bilin4(base, sx, sy, c4);
        acc.x = fmaf(v.x, wk, acc.x);
        acc.y = fmaf(v.y, wk, acc.y);
        acc.z = fmaf(v.z, wk, acc.z);
        acc.w = fmaf(v.w, wk, acc.w);
    }
    out4[(size_t)p * 16 + c4] = acc;
}

// ---------------- small fallback: CHW, wave per point (no workspace) ----------------
__device__ __forceinline__ float bilin_chw(const float* __restrict__ feat, int b, int lane,
                                           float gx, float gy) {
    float ix = clampf((gx + 1.0f) * 0.5f * 255.0f, 0.0f, 255.0f);
    float iy = clampf((gy + 1.0f) * 0.5f * 255.0f, 0.0f, 255.0f);
    float x0f = floorf(ix), y0f = floorf(iy);
    float wx = ix - x0f, wy = iy - y0f;
    int x0 = (int)x0f, y0 = (int)y0f;
    int x1 = min(x0 + 1, 255), y1 = min(y0 + 1, 255);
    const float* base = feat + ((size_t)b * CC + lane) * (HH * WW);
    float f00 = base[(y0 << 8) + x0];
    float f01 = base[(y0 << 8) + x1];
    float f10 = base[(y1 << 8) + x0];
    float f11 = base[(y1 << 8) + x1];
    float omx = 1.0f - wx, omy = 1.0f - wy;
    return (f00 * omx + f01 * wx) * omy + (f10 * omx + f11 * wx) * wy;
}

__global__ void __launch_bounds__(256) fallback_kernel(const float* __restrict__ feat,
                                                       const float* __restrict__ coords,
                                                       const float* __restrict__ cell,
                                                       const float* __restrict__ W1,
                                                       const float* __restrict__ b1,
                                                       const float* __restrict__ Wr,
                                                       const float* __restrict__ br,
                                                       const float* __restrict__ W2,
                                                       const float* __restrict__ b2,
                                                       float* __restrict__ out) {
    int lane = threadIdx.x & 63;
    int wave = threadIdx.x >> 6;
    int pidx = blockIdx.x * 4 + wave;
    if (pidx >= NPTS) return;
    int b = pidx >> 14;
    float gx = coords[(size_t)pidx * 2 + 0];
    float gy = coords[(size_t)pidx * 2 + 1];
    float cx = cell[(size_t)pidx * 2 + 0];
    float cy = cell[(size_t)pidx * 2 + 1];
    float fa = bilin_chw(feat, b, lane, gx, gy);
    float h = b1[lane];
#pragma unroll
    for (int i = 0; i < 64; ++i) {
        float a = __shfl(fa, i, 64);
        h = fmaf(a, W1[i * 64 + lane], h);
    }
    h = fmaf(gx, W1[64 * 64 + lane], h);
    h = fmaf(gy, W1[65 * 64 + lane], h);
    h = fmaf(cx, W1[66 * 64 + lane], h);
    h = fmaf(cy, W1[67 * 64 + lane], h);
    h = leaky_f(h);
    float h2 = br[lane];
#pragma unroll
    for (int i = 0; i < 64; ++i) {
        float a = __shfl(h, i, 64);
        h2 = fmaf(a, Wr[i * 64 + lane], h2);
    }
    h2 = leaky_f(h + h2);
    int j = lane < 29 ? lane : 0;
    float o = b2[j];
#pragma unroll
    for (int i = 0; i < 64; ++i) {
        float a = __shfl(h2, i, 64);
        o = fmaf(a, W2[i * 29 + j], o);
    }
    int kk = lane < K_TAPS ? lane : 0;
    float r_raw = __shfl(o, 0, 64);
    float s_raw = __shfl(o, 1, 64);
    float rx_raw = __shfl(o, 2 + 2 * kk, 64);
    float ry_raw = __shfl(o, 3 + 2 * kk, 64);
    float g_raw = __shfl(o, 20 + kk, 64);
    float r = clampf(softplus_f(r_raw) + 0.1f, 0.1f, 4.0f);
    float sg = clampf(softplus_f(s_raw) + 0.5f, 0.5f, 6.0f);
    float bx = (float)(kk % 3 - 1);
    float by = (float)(kk / 3 - 1);
    float offx = fmaf(r, bx, tanhf(rx_raw) * 0.5f);
    float offy = fmaf(r, by, tanhf(ry_raw) * 0.5f);
    float d2 = offx * offx + offy * offy;
    float se = sg * 2.0f;
    float wgeo = expf(-0.5f * d2 / (se * se + 1e-8f));
    float gate = 1.0f / (1.0f + expf(-g_raw));
    float w = wgeo * gate;
    float wv = (lane < K_TAPS) ? w : 0.0f;
#pragma unroll
    for (int m = 32; m >= 1; m >>= 1) wv += __shfl_xor(wv, m, 64);
    float wn = w / (wv + 1e-8f);
    float acc = 0.0f;
#pragma unroll
    for (int k = 0; k < K_TAPS; ++k) {
        float ox = __shfl(offx, k, 64) * SCLX;
        float oy = __shfl(offy, k, 64) * SCLY;
        float wk2 = __shfl(wn, k, 64);
        float fv = bilin_chw(feat, b, lane, gx + ox, gy + oy);
        acc = fmaf(fv, wk2, acc);
    }
    out[(size_t)pidx * CC + lane] = acc;
}

extern "C" void kernel_launch(void* const* d_in, const int* in_sizes, int n_in,
                              void* d_out, int out_size, void* d_ws, size_t ws_size,
                              hipStream_t stream) {
    const float* feat = (const float*)d_in[0];
    const float* coords = (const float*)d_in[1];
    const float* cell = (const float*)d_in[2];
    const float* W1 = (const float*)d_in[3];
    const float* b1 = (const float*)d_in[4];
    const float* Wr = (const float*)d_in[5];
    const float* br = (const float*)d_in[6];
    const float* W2 = (const float*)d_in[7];
    const float* b2 = (const float*)d_in[8];
    float* out = (float*)d_out;

    const size_t needT = (size_t)BB * HH * WW * CC * sizeof(float);  // 64 MB
    const size_t needP = (size_t)NPTS * PRM_STRIDE * sizeof(float);  // 8 MB

    if (ws_size >= needT + needP) {
        float* featT = (float*)d_ws;
        float* prm = (float*)((char*)d_ws + needT);
        dim3 tg((HH * WW) / 64, BB);
        transpose_kernel<<<tg, 256, 0, stream>>>(feat, featT);
        mlp_kernel<<<NPTS / 64, 256, 0, stream>>>((const float4*)featT, coords, cell, W1, b1,
                                                  Wr, br, W2, b2, prm);
        gather_kernel<<<(NPTS * 16) / 256, 256, 0, stream>>>((const float4*)featT, prm,
                                                             (float4*)out);
    } else {
        fallback_kernel<<<NPTS / 4, 256, 0, stream>>>(feat, coords, cell, W1, b1, Wr, br, W2,
                                                      b2, out);
    }
}

// Round 8
// 81.901 us; speedup vs baseline: 2.3481x; 1.4272x over previous
//
#include <hip/hip_runtime.h>

#define K_TAPS 9
#define CC 64
#define HH 256
#define WW 256
#define BB 4
#define NN 16384
#define NPTS (BB * NN)
#define SCLX (2.0f / 255.0f)
#define SCLY (2.0f / 255.0f)
#define PRM_STRIDE 32
#define AS 68  // act row stride (floats)

__device__ __forceinline__ float softplus_f(float x) {
    return fmaxf(x, 0.0f) + log1pf(expf(-fabsf(x)));
}
__device__ __forceinline__ float leaky_f(float x) { return x >= 0.0f ? x : 0.2f * x; }
__device__ __forceinline__ float clampf(float x, float lo, float hi) {
    return fminf(fmaxf(x, lo), hi);
}
__device__ __forceinline__ float bf2f(unsigned short u) {
    union { unsigned int i; float f; } v;
    v.i = (unsigned int)u << 16;
    return v.f;
}
__device__ __forceinline__ unsigned short f2bf(float f) {
    union { float f; unsigned int i; } v;
    v.f = f;
    unsigned int r = (v.i + 0x7FFFu + ((v.i >> 16) & 1u)) >> 16;
    return (unsigned short)r;
}

// transpose (B, C, H*W) fp32 -> (B, H*W, C) bf16
__global__ void __launch_bounds__(256) transpose_kernel(const float* __restrict__ feat,
                                                        unsigned int* __restrict__ featB) {
    __shared__ float tile[64][65];
    int b = blockIdx.y;
    int p0 = blockIdx.x * 64;
    int tp = threadIdx.x & 63;
    int tq = threadIdx.x >> 6;
    const float* fb = feat + (size_t)b * CC * HH * WW;
#pragma unroll
    for (int i = 0; i < 16; ++i) {
        int c = tq * 16 + i;
        tile[c][tp] = fb[(size_t)c * (HH * WW) + p0 + tp];
    }
    __syncthreads();
    // write bf16 pairs: uint at ((b*HW + p0 + p)*32 + c2)
    unsigned int* ob = featB + ((size_t)b * (HH * WW) + p0) * 32;
    int c2 = threadIdx.x & 31;       // channel pair 0..31
    int psub = threadIdx.x >> 5;     // 0..7
#pragma unroll
    for (int i = 0; i < 8; ++i) {
        int p = i * 8 + psub;
        unsigned int lo = f2bf(tile[2 * c2][p]);
        unsigned int hi = f2bf(tile[2 * c2 + 1][p]);
        ob[(size_t)p * 32 + c2] = lo | (hi << 16);
    }
}

// bilinear sample of 4 bf16 channels at grid coords (gx,gy); c4 = channel quad
__device__ __forceinline__ float4 bilin4_bf(const unsigned short* __restrict__ base, float gx,
                                            float gy, int c4) {
    float ix = clampf((gx + 1.0f) * 0.5f * 255.0f, 0.0f, 255.0f);
    float iy = clampf((gy + 1.0f) * 0.5f * 255.0f, 0.0f, 255.0f);
    float x0f = floorf(ix), y0f = floorf(iy);
    float wx = ix - x0f, wy = iy - y0f;
    int x0 = (int)x0f, y0 = (int)y0f;
    int x1 = min(x0 + 1, 255), y1 = min(y0 + 1, 255);
    const ushort4 u00 = *(const ushort4*)(base + (size_t)(((y0 << 8) + x0) * 64) + c4 * 4);
    const ushort4 u01 = *(const ushort4*)(base + (size_t)(((y0 << 8) + x1) * 64) + c4 * 4);
    const ushort4 u10 = *(const ushort4*)(base + (size_t)(((y1 << 8) + x0) * 64) + c4 * 4);
    const ushort4 u11 = *(const ushort4*)(base + (size_t)(((y1 << 8) + x1) * 64) + c4 * 4);
    float w00 = (1.0f - wx) * (1.0f - wy), w01 = wx * (1.0f - wy);
    float w10 = (1.0f - wx) * wy, w11 = wx * wy;
    float4 v;
    v.x = bf2f(u00.x) * w00 + bf2f(u01.x) * w01 + bf2f(u10.x) * w10 + bf2f(u11.x) * w11;
    v.y = bf2f(u00.y) * w00 + bf2f(u01.y) * w01 + bf2f(u10.y) * w10 + bf2f(u11.y) * w11;
    v.z = bf2f(u00.z) * w00 + bf2f(u01.z) * w01 + bf2f(u10.z) * w10 + bf2f(u11.z) * w11;
    v.w = bf2f(u00.w) * w00 + bf2f(u01.w) * w01 + bf2f(u10.w) * w01 * 0.0f +
          bf2f(u10.w) * w10 + bf2f(u11.w) * w11;  // (kept explicit below)
    // recompute w cleanly to avoid the line above being wrong:
    v.w = bf2f(u00.w) * w00 + bf2f(u01.w) * w01 + bf2f(u10.w) * w10 + bf2f(u11.w) * w11;
    return v;
}

// ---------------- K2: register-blocked MLP, 64 points/block, 4x4 tile/thread ----------------
// Weights staged in LDS. Inner loop: 2 x ds_read_b128 + 16 FMA.
__global__ void __launch_bounds__(256) mlp_kernel(const unsigned short* __restrict__ featB,
                                                  const float* __restrict__ coords,
                                                  const float* __restrict__ cell,
                                                  const float* __restrict__ W1,
                                                  const float* __restrict__ b1,
                                                  const float* __restrict__ Wr,
                                                  const float* __restrict__ br,
                                                  const float* __restrict__ W2,
                                                  const float* __restrict__ b2,
                                                  float* __restrict__ prm) {
    __shared__ __align__(16) float act[68 * AS];   // [feature i][point 0..63]
    __shared__ __align__(16) float wbuf[68 * 64];  // W1 -> Wr -> (W2 | sot)
    float4* wbuf4 = (float4*)wbuf;

    const int t = threadIdx.x;
    const int q = t & 15;
    const int pgrp = t >> 4;
    const int blk0 = blockIdx.x * 64;

    // ---- stage W1 into LDS (in flight across phase A) ----
    {
        const float4* w1g = (const float4*)W1;  // 1088 float4
#pragma unroll
        for (int idx = t; idx < 1088; idx += 256) wbuf4[idx] = w1g[idx];
    }

    // ---- Phase A: anchor bilinear gather (bf16 featT) ----
    {
        const int pt = t & 63;
        const int wvi = t >> 6;
        const int pg = blk0 + pt;
        const int bb = pg >> 14;
        const float gx = coords[2 * pg], gy = coords[2 * pg + 1];
        float ix = clampf((gx + 1.0f) * 0.5f * 255.0f, 0.0f, 255.0f);
        float iy = clampf((gy + 1.0f) * 0.5f * 255.0f, 0.0f, 255.0f);
        float x0f = floorf(ix), y0f = floorf(iy);
        float wx = ix - x0f, wy = iy - y0f;
        int x0 = (int)x0f, y0 = (int)y0f;
        int x1 = min(x0 + 1, 255), y1 = min(y0 + 1, 255);
        const unsigned short* base = featB + (size_t)bb * (HH * WW) * 64;
        size_t i00 = (size_t)(((y0 << 8) + x0) * 64), i01 = (size_t)(((y0 << 8) + x1) * 64);
        size_t i10 = (size_t)(((y1 << 8) + x0) * 64), i11 = (size_t)(((y1 << 8) + x1) * 64);
        float w00 = (1.0f - wx) * (1.0f - wy), w01 = wx * (1.0f - wy);
        float w10 = (1.0f - wx) * wy, w11 = wx * wy;
#pragma unroll
        for (int g = 0; g < 4; ++g) {
            int qq = 4 * g + wvi;
            ushort4 u00 = *(const ushort4*)(base + i00 + qq * 4);
            ushort4 u01 = *(const ushort4*)(base + i01 + qq * 4);
            ushort4 u10 = *(const ushort4*)(base + i10 + qq * 4);
            ushort4 u11 = *(const ushort4*)(base + i11 + qq * 4);
            act[(4 * qq + 0) * AS + pt] =
                bf2f(u00.x) * w00 + bf2f(u01.x) * w01 + bf2f(u10.x) * w10 + bf2f(u11.x) * w11;
            act[(4 * qq + 1) * AS + pt] =
                bf2f(u00.y) * w00 + bf2f(u01.y) * w01 + bf2f(u10.y) * w10 + bf2f(u11.y) * w11;
            act[(4 * qq + 2) * AS + pt] =
                bf2f(u00.z) * w00 + bf2f(u01.z) * w01 + bf2f(u10.z) * w10 + bf2f(u11.z) * w11;
            act[(4 * qq + 3) * AS + pt] =
                bf2f(u00.w) * w00 + bf2f(u01.w) * w01 + bf2f(u10.w) * w10 + bf2f(u11.w) * w11;
        }
        if (wvi == 0) {
            act[64 * AS + pt] = gx;
            act[65 * AS + pt] = gy;
            act[66 * AS + pt] = cell[2 * pg];
            act[67 * AS + pt] = cell[2 * pg + 1];
        }
    }
    __syncthreads();

    // ---- Layer 1 ----
    float hres[4][4];
    {
        float acc[4][4];
        float4 b4 = ((const float4*)b1)[q];
        float bj[4] = {b4.x, b4.y, b4.z, b4.w};
#pragma unroll
        for (int j = 0; j < 4; ++j)
#pragma unroll
            for (int p = 0; p < 4; ++p) acc[j][p] = bj[j];
#pragma unroll 4
        for (int i = 0; i < 68; ++i) {
            float4 av = *(const float4*)&act[i * AS + 4 * pgrp];
            float4 wv4 = *(const float4*)&wbuf[i * 64 + 4 * q];
            float a[4] = {av.x, av.y, av.z, av.w};
            float wj[4] = {wv4.x, wv4.y, wv4.z, wv4.w};
#pragma unroll
            for (int j = 0; j < 4; ++j)
#pragma unroll
                for (int p = 0; p < 4; ++p) acc[j][p] = fmaf(a[p], wj[j], acc[j][p]);
        }
#pragma unroll
        for (int j = 0; j < 4; ++j)
#pragma unroll
            for (int p = 0; p < 4; ++p) hres[j][p] = leaky_f(acc[j][p]);
    }
    __syncthreads();

#pragma unroll
    for (int j = 0; j < 4; ++j)
        *(float4*)&act[(4 * q + j) * AS + 4 * pgrp] =
            make_float4(hres[j][0], hres[j][1], hres[j][2], hres[j][3]);
    {
        const float4* wrg = (const float4*)Wr;  // 1024 float4
#pragma unroll
        for (int idx = t; idx < 1024; idx += 256) wbuf4[idx] = wrg[idx];
    }
    __syncthreads();

    // ---- Layer 2 ----
    float h2[4][4];
    {
        float4 b4 = ((const float4*)br)[q];
        float bj[4] = {b4.x, b4.y, b4.z, b4.w};
#pragma unroll
        for (int j = 0; j < 4; ++j)
#pragma unroll
            for (int p = 0; p < 4; ++p) h2[j][p] = bj[j];
#pragma unroll 4
        for (int i = 0; i < 64; ++i) {
            float4 av = *(const float4*)&act[i * AS + 4 * pgrp];
            float4 wv4 = *(const float4*)&wbuf[i * 64 + 4 * q];
            float a[4] = {av.x, av.y, av.z, av.w};
            float wj[4] = {wv4.x, wv4.y, wv4.z, wv4.w};
#pragma unroll
            for (int j = 0; j < 4; ++j)
#pragma unroll
                for (int p = 0; p < 4; ++p) h2[j][p] = fmaf(a[p], wj[j], h2[j][p]);
        }
#pragma unroll
        for (int j = 0; j < 4; ++j)
#pragma unroll
            for (int p = 0; p < 4; ++p) h2[j][p] = leaky_f(hres[j][p] + h2[j][p]);
    }
    __syncthreads();

#pragma unroll
    for (int j = 0; j < 4; ++j)
        *(float4*)&act[(4 * q + j) * AS + 4 * pgrp] =
            make_float4(h2[j][0], h2[j][1], h2[j][2], h2[j][3]);
    {
        const float4* w2g = (const float4*)W2;  // 464 float4
#pragma unroll
        for (int idx = t; idx < 464; idx += 256) wbuf4[idx] = w2g[idx];
    }
    __syncthreads();

    float* sot = wbuf + 2048;  // [64][30] overlay past W2

    // ---- Layer 3 ----
    {
        const int j0 = 2 * q, j1 = 2 * q + 1;
        const int jj0 = min(j0, 28), jj1 = min(j1, 28);
        float o0[4], o1[4];
        float bb0 = b2[jj0], bb1 = b2[jj1];
#pragma unroll
        for (int p = 0; p < 4; ++p) {
            o0[p] = bb0;
            o1[p] = bb1;
        }
#pragma unroll 4
        for (int i = 0; i < 64; ++i) {
            float4 av = *(const float4*)&act[i * AS + 4 * pgrp];
            float a[4] = {av.x, av.y, av.z, av.w};
            float w0 = wbuf[i * 29 + jj0], w1 = wbuf[i * 29 + jj1];
#pragma unroll
            for (int p = 0; p < 4; ++p) {
                o0[p] = fmaf(a[p], w0, o0[p]);
                o1[p] = fmaf(a[p], w1, o1[p]);
            }
        }
#pragma unroll
        for (int p = 0; p < 4; ++p) {
            int pt = 4 * pgrp + p;
            if (j0 < 29) sot[pt * 30 + j0] = o0[p];
            if (j1 < 29) sot[pt * 30 + j1] = o1[p];
        }
    }
    __syncthreads();

    // ---- Head: 4 threads/point ----
    {
        const int pt = t >> 2, sub = t & 3;
        const int pg = blk0 + pt;
        const float* so = sot + pt * 30;
        float gx = coords[2 * pg], gy = coords[2 * pg + 1];
        float r = clampf(softplus_f(so[0]) + 0.1f, 0.1f, 4.0f);
        float sg = clampf(softplus_f(so[1]) + 0.5f, 0.5f, 6.0f);
        float se = sg * 2.0f;
        float inv2 = -0.5f / (se * se + 1e-8f);
        float sx[3], sy[3], wv[3];
        float s = 0.0f;
#pragma unroll
        for (int ii = 0; ii < 3; ++ii) {
            int kr = 4 * ii + sub;
            int k = kr < 9 ? kr : 0;
            float bx = (float)(k % 3 - 1);
            float by = (float)(k / 3 - 1);
            float ox = fmaf(r, bx, tanhf(so[2 + 2 * k]) * 0.5f);
            float oy = fmaf(r, by, tanhf(so[3 + 2 * k]) * 0.5f);
            float d2 = ox * ox + oy * oy;
            float wgeo = expf(d2 * inv2);
            float gate = 1.0f / (1.0f + expf(-so[20 + k]));
            float w = (kr < 9) ? wgeo * gate : 0.0f;
            wv[ii] = w;
            s += w;
            sx[ii] = fmaf(ox, SCLX, gx);
            sy[ii] = fmaf(oy, SCLY, gy);
        }
        s += __shfl_xor(s, 1, 64);
        s += __shfl_xor(s, 2, 64);
        float inv = 1.0f / (s + 1e-8f);
        float* pp = prm + (size_t)pg * PRM_STRIDE;
#pragma unroll
        for (int ii = 0; ii < 3; ++ii) {
            int kr = 4 * ii + sub;
            if (kr < 9) {
                pp[3 * kr + 0] = sx[ii];
                pp[3 * kr + 1] = sy[ii];
                pp[3 * kr + 2] = wv[ii] * inv;
            }
        }
    }
}

// ---------------- K3: deformable gather (bf16 featT), thread = (point, channel-quad) --------
__global__ void __launch_bounds__(256) gather_kernel(const unsigned short* __restrict__ featB,
                                                     const float* __restrict__ prm,
                                                     float4* __restrict__ out4) {
    int tid = blockIdx.x * 256 + threadIdx.x;
    int c4 = tid & 15;
    int p = tid >> 4;
    int bb = p >> 14;
    const unsigned short* base = featB + (size_t)bb * (HH * WW) * 64;
    const float* pp = prm + (size_t)p * PRM_STRIDE;
    float4 acc = make_float4(0.0f, 0.0f, 0.0f, 0.0f);
#pragma unroll 3
    for (int k = 0; k < K_TAPS; ++k) {
        float sx = pp[3 * k + 0];
        float sy = pp[3 * k + 1];
        float wk = pp[3 * k + 2];
        float4 v = bilin4_bf(base, sx, sy, c4);
        acc.x = fmaf(v.x, wk, acc.x);
        acc.y = fmaf(v.y, wk, acc.y);
        acc.z = fmaf(v.z, wk, acc.z);
        acc.w = fmaf(v.w, wk, acc.w);
    }
    out4[(size_t)p * 16 + c4] = acc;
}

// ---------------- small fallback: CHW fp32, wave per point (no workspace) ----------------
__device__ __forceinline__ float bilin_chw(const float* __restrict__ feat, int b, int lane,
                                           float gx, float gy) {
    float ix = clampf((gx + 1.0f) * 0.5f * 255.0f, 0.0f, 255.0f);
    float iy = clampf((gy + 1.0f) * 0.5f * 255.0f, 0.0f, 255.0f);
    float x0f = floorf(ix), y0f = floorf(iy);
    float wx = ix - x0f, wy = iy - y0f;
    int x0 = (int)x0f, y0 = (int)y0f;
    int x1 = min(x0 + 1, 255), y1 = min(y0 + 1, 255);
    const float* base = feat + ((size_t)b * CC + lane) * (HH * WW);
    float f00 = base[(y0 << 8) + x0];
    float f01 = base[(y0 << 8) + x1];
    float f10 = base[(y1 << 8) + x0];
    float f11 = base[(y1 << 8) + x1];
    float omx = 1.0f - wx, omy = 1.0f - wy;
    return (f00 * omx + f01 * wx) * omy + (f10 * omx + f11 * wx) * wy;
}

__global__ void __launch_bounds__(256) fallback_kernel(const float* __restrict__ feat,
                                                       const float* __restrict__ coords,
                                                       const float* __restrict__ cell,
                                                       const float* __restrict__ W1,
                                                       const float* __restrict__ b1,
                                                       const float* __restrict__ Wr,
                                                       const float* __restrict__ br,
                                                       const float* __restrict__ W2,
                                                       const float* __restrict__ b2,
                                                       float* __restrict__ out) {
    int lane = threadIdx.x & 63;
    int wave = threadIdx.x >> 6;
    int pidx = blockIdx.x * 4 + wave;
    if (pidx >= NPTS) return;
    int b = pidx >> 14;
    float gx = coords[(size_t)pidx * 2 + 0];
    float gy = coords[(size_t)pidx * 2 + 1];
    float cx = cell[(size_t)pidx * 2 + 0];
    float cy = cell[(size_t)pidx * 2 + 1];
    float fa = bilin_chw(feat, b, lane, gx, gy);
    float h = b1[lane];
#pragma unroll
    for (int i = 0; i < 64; ++i) {
        float a = __shfl(fa, i, 64);
        h = fmaf(a, W1[i * 64 + lane], h);
    }
    h = fmaf(gx, W1[64 * 64 + lane], h);
    h = fmaf(gy, W1[65 * 64 + lane], h);
    h = fmaf(cx, W1[66 * 64 + lane], h);
    h = fmaf(cy, W1[67 * 64 + lane], h);
    h = leaky_f(h);
    float h2 = br[lane];
#pragma unroll
    for (int i = 0; i < 64; ++i) {
        float a = __shfl(h, i, 64);
        h2 = fmaf(a, Wr[i * 64 + lane], h2);
    }
    h2 = leaky_f(h + h2);
    int j = lane < 29 ? lane : 0;
    float o = b2[j];
#pragma unroll
    for (int i = 0; i < 64; ++i) {
        float a = __shfl(h2, i, 64);
        o = fmaf(a, W2[i * 29 + j], o);
    }
    int kk = lane < K_TAPS ? lane : 0;
    float r_raw = __shfl(o, 0, 64);
    float s_raw = __shfl(o, 1, 64);
    float rx_raw = __shfl(o, 2 + 2 * kk, 64);
    float ry_raw = __shfl(o, 3 + 2 * kk, 64);
    float g_raw = __shfl(o, 20 + kk, 64);
    float r = clampf(softplus_f(r_raw) + 0.1f, 0.1f, 4.0f);
    float sg = clampf(softplus_f(s_raw) + 0.5f, 0.5f, 6.0f);
    float bx = (float)(kk % 3 - 1);
    float by = (float)(kk / 3 - 1);
    float offx = fmaf(r, bx, tanhf(rx_raw) * 0.5f);
    float offy = fmaf(r, by, tanhf(ry_raw) * 0.5f);
    float d2 = offx * offx + offy * offy;
    float se = sg * 2.0f;
    float wgeo = expf(-0.5f * d2 / (se * se + 1e-8f));
    float gate = 1.0f / (1.0f + expf(-g_raw));
    float w = wgeo * gate;
    float wv = (lane < K_TAPS) ? w : 0.0f;
#pragma unroll
    for (int m = 32; m >= 1; m >>= 1) wv += __shfl_xor(wv, m, 64);
    float wn = w / (wv + 1e-8f);
    float acc = 0.0f;
#pragma unroll
    for (int k = 0; k < K_TAPS; ++k) {
        float ox = __shfl(offx, k, 64) * SCLX;
        float oy = __shfl(offy, k, 64) * SCLY;
        float wk2 = __shfl(wn, k, 64);
        float fv = bilin_chw(feat, b, lane, gx + ox, gy + oy);
        acc = fmaf(fv, wk2, acc);
    }
    out[(size_t)pidx * CC + lane] = acc;
}

extern "C" void kernel_launch(void* const* d_in, const int* in_sizes, int n_in,
                              void* d_out, int out_size, void* d_ws, size_t ws_size,
                              hipStream_t stream) {
    const float* feat = (const float*)d_in[0];
    const float* coords = (const float*)d_in[1];
    const float* cell = (const float*)d_in[2];
    const float* W1 = (const float*)d_in[3];
    const float* b1 = (const float*)d_in[4];
    const float* Wr = (const float*)d_in[5];
    const float* br = (const float*)d_in[6];
    const float* W2 = (const float*)d_in[7];
    const float* b2 = (const float*)d_in[8];
    float* out = (float*)d_out;

    const size_t needT = (size_t)BB * HH * WW * CC * sizeof(unsigned short);  // 32 MB
    const size_t needP = (size_t)NPTS * PRM_STRIDE * sizeof(float);           // 8 MB

    if (ws_size >= needT + needP) {
        unsigned short* featB = (unsigned short*)d_ws;
        float* prm = (float*)((char*)d_ws + needT);
        dim3 tg((HH * WW) / 64, BB);
        transpose_kernel<<<tg, 256, 0, stream>>>(feat, (unsigned int*)featB);
        mlp_kernel<<<NPTS / 64, 256, 0, stream>>>(featB, coords, cell, W1, b1, Wr, br, W2, b2,
                                                  prm);
        gather_kernel<<<(NPTS * 16) / 256, 256, 0, stream>>>(featB, prm, (float4*)out);
    } else {
        fallback_kernel<<<NPTS / 4, 256, 0, stream>>>(feat, coords, cell, W1, b1, Wr, br, W2,
                                                      b2, out);
    }
}

// Round 9
// 73.635 us; speedup vs baseline: 2.6117x; 1.1123x over previous
//
#include <hip/hip_runtime.h>

#define K_TAPS 9
#define CC 64
#define HH 256
#define WW 256
#define BB 4
#define NN 16384
#define NPTS (BB * NN)
#define SCLX (2.0f / 255.0f)
#define SCLY (2.0f / 255.0f)
#define PRM_STRIDE 32
#define AS 68  // act row stride (floats)

__device__ __forceinline__ float softplus_f(float x) {
    return fmaxf(x, 0.0f) + log1pf(expf(-fabsf(x)));
}
__device__ __forceinline__ float leaky_f(float x) { return x >= 0.0f ? x : 0.2f * x; }
__device__ __forceinline__ float clampf(float x, float lo, float hi) {
    return fminf(fmaxf(x, lo), hi);
}
__device__ __forceinline__ float bf2f(unsigned short u) {
    union { unsigned int i; float f; } v;
    v.i = (unsigned int)u << 16;
    return v.f;
}
__device__ __forceinline__ unsigned short f2bf(float f) {
    union { float f; unsigned int i; } v;
    v.f = f;
    unsigned int r = (v.i + 0x7FFFu + ((v.i >> 16) & 1u)) >> 16;
    return (unsigned short)r;
}

// transpose (B, C, H*W) fp32 -> (B, H*W, C) bf16
__global__ void __launch_bounds__(256) transpose_kernel(const float* __restrict__ feat,
                                                        unsigned int* __restrict__ featB) {
    __shared__ float tile[64][65];
    int b = blockIdx.y;
    int p0 = blockIdx.x * 64;
    int tp = threadIdx.x & 63;
    int tq = threadIdx.x >> 6;
    const float* fb = feat + (size_t)b * CC * HH * WW;
#pragma unroll
    for (int i = 0; i < 16; ++i) {
        int c = tq * 16 + i;
        tile[c][tp] = fb[(size_t)c * (HH * WW) + p0 + tp];
    }
    __syncthreads();
    unsigned int* ob = featB + ((size_t)b * (HH * WW) + p0) * 32;
    int c2 = threadIdx.x & 31;    // channel pair
    int psub = threadIdx.x >> 5;  // 0..7
#pragma unroll
    for (int i = 0; i < 8; ++i) {
        int p = i * 8 + psub;
        unsigned int lo = f2bf(tile[2 * c2][p]);
        unsigned int hi = f2bf(tile[2 * c2 + 1][p]);
        ob[(size_t)p * 32 + c2] = lo | (hi << 16);
    }
}

// bilinear sample of 4 bf16 channels at grid coords (gx,gy); c4 = channel quad
__device__ __forceinline__ float4 bilin4_bf(const unsigned short* __restrict__ base, float gx,
                                            float gy, int c4) {
    float ix = clampf((gx + 1.0f) * 0.5f * 255.0f, 0.0f, 255.0f);
    float iy = clampf((gy + 1.0f) * 0.5f * 255.0f, 0.0f, 255.0f);
    float x0f = floorf(ix), y0f = floorf(iy);
    float wx = ix - x0f, wy = iy - y0f;
    int x0 = (int)x0f, y0 = (int)y0f;
    int x1 = min(x0 + 1, 255), y1 = min(y0 + 1, 255);
    const ushort4 u00 = *(const ushort4*)(base + (size_t)(((y0 << 8) + x0) * 64) + c4 * 4);
    const ushort4 u01 = *(const ushort4*)(base + (size_t)(((y0 << 8) + x1) * 64) + c4 * 4);
    const ushort4 u10 = *(const ushort4*)(base + (size_t)(((y1 << 8) + x0) * 64) + c4 * 4);
    const ushort4 u11 = *(const ushort4*)(base + (size_t)(((y1 << 8) + x1) * 64) + c4 * 4);
    float w00 = (1.0f - wx) * (1.0f - wy), w01 = wx * (1.0f - wy);
    float w10 = (1.0f - wx) * wy, w11 = wx * wy;
    float4 v;
    v.x = bf2f(u00.x) * w00 + bf2f(u01.x) * w01 + bf2f(u10.x) * w10 + bf2f(u11.x) * w11;
    v.y = bf2f(u00.y) * w00 + bf2f(u01.y) * w01 + bf2f(u10.y) * w10 + bf2f(u11.y) * w11;
    v.z = bf2f(u00.z) * w00 + bf2f(u01.z) * w01 + bf2f(u10.z) * w10 + bf2f(u11.z) * w11;
    v.w = bf2f(u00.w) * w00 + bf2f(u01.w) * w01 + bf2f(u10.w) * w10 + bf2f(u11.w) * w11;
    return v;
}

// ---------------- fused: anchor + MLP + head + deformable gather; 64 points/block ----------
__global__ void __launch_bounds__(256) fused_kernel(const unsigned short* __restrict__ featB,
                                                    const float* __restrict__ coords,
                                                    const float* __restrict__ cell,
                                                    const float* __restrict__ W1,
                                                    const float* __restrict__ b1,
                                                    const float* __restrict__ Wr,
                                                    const float* __restrict__ br,
                                                    const float* __restrict__ W2,
                                                    const float* __restrict__ b2,
                                                    float4* __restrict__ out4) {
    __shared__ __align__(16) float act[68 * AS];   // [feature i][point 0..63]
    __shared__ __align__(16) float wbuf[68 * 64];  // W1 -> Wr -> (W2 | sot) -> (prm | sot)
    float4* wbuf4 = (float4*)wbuf;

    const int t = threadIdx.x;
    const int q = t & 15;
    const int pgrp = t >> 4;
    const int blk0 = blockIdx.x * 64;

    // ---- Phase A: issue W1 staging loads, then anchor corner loads, then LDS writes ----
    {
        const int pt = t & 63;
        const int wvi = t >> 6;
        const int pg = blk0 + pt;
        const int bb = pg >> 14;
        const float gx = coords[2 * pg], gy = coords[2 * pg + 1];

        // W1 staging loads (1088 float4): 4 full rounds + partial (t<64)
        const float4* w1g = (const float4*)W1;
        float4 w1r0 = w1g[t];
        float4 w1r1 = w1g[t + 256];
        float4 w1r2 = w1g[t + 512];
        float4 w1r3 = w1g[t + 768];
        float4 w1x;
        if (t < 64) w1x = w1g[1024 + t];

        // anchor corner loads
        float ix = clampf((gx + 1.0f) * 0.5f * 255.0f, 0.0f, 255.0f);
        float iy = clampf((gy + 1.0f) * 0.5f * 255.0f, 0.0f, 255.0f);
        float x0f = floorf(ix), y0f = floorf(iy);
        float wx = ix - x0f, wy = iy - y0f;
        int x0 = (int)x0f, y0 = (int)y0f;
        int x1 = min(x0 + 1, 255), y1 = min(y0 + 1, 255);
        const unsigned short* base = featB + (size_t)bb * (HH * WW) * 64;
        size_t i00 = (size_t)(((y0 << 8) + x0) * 64), i01 = (size_t)(((y0 << 8) + x1) * 64);
        size_t i10 = (size_t)(((y1 << 8) + x0) * 64), i11 = (size_t)(((y1 << 8) + x1) * 64);
        ushort4 u00[4], u01[4], u10[4], u11[4];
#pragma unroll
        for (int g = 0; g < 4; ++g) {
            int qq = 4 * g + wvi;
            u00[g] = *(const ushort4*)(base + i00 + qq * 4);
            u01[g] = *(const ushort4*)(base + i01 + qq * 4);
            u10[g] = *(const ushort4*)(base + i10 + qq * 4);
            u11[g] = *(const ushort4*)(base + i11 + qq * 4);
        }

        // W1 -> LDS
        wbuf4[t] = w1r0;
        wbuf4[t + 256] = w1r1;
        wbuf4[t + 512] = w1r2;
        wbuf4[t + 768] = w1r3;
        if (t < 64) wbuf4[1024 + t] = w1x;

        // combine corners -> act
        float w00 = (1.0f - wx) * (1.0f - wy), w01 = wx * (1.0f - wy);
        float w10 = (1.0f - wx) * wy, w11 = wx * wy;
#pragma unroll
        for (int g = 0; g < 4; ++g) {
            int qq = 4 * g + wvi;
            act[(4 * qq + 0) * AS + pt] = bf2f(u00[g].x) * w00 + bf2f(u01[g].x) * w01 +
                                          bf2f(u10[g].x) * w10 + bf2f(u11[g].x) * w11;
            act[(4 * qq + 1) * AS + pt] = bf2f(u00[g].y) * w00 + bf2f(u01[g].y) * w01 +
                                          bf2f(u10[g].y) * w10 + bf2f(u11[g].y) * w11;
            act[(4 * qq + 2) * AS + pt] = bf2f(u00[g].z) * w00 + bf2f(u01[g].z) * w01 +
                                          bf2f(u10[g].z) * w10 + bf2f(u11[g].z) * w11;
            act[(4 * qq + 3) * AS + pt] = bf2f(u00[g].w) * w00 + bf2f(u01[g].w) * w01 +
                                          bf2f(u10[g].w) * w10 + bf2f(u11[g].w) * w11;
        }
        if (wvi == 0) {
            act[64 * AS + pt] = gx;
            act[65 * AS + pt] = gy;
            act[66 * AS + pt] = cell[2 * pg];
            act[67 * AS + pt] = cell[2 * pg + 1];
        }
    }
    __syncthreads();

    // ---- Layer 1 ----
    float hres[4][4];
    {
        float acc[4][4];
        float4 b4 = ((const float4*)b1)[q];
        float bj[4] = {b4.x, b4.y, b4.z, b4.w};
#pragma unroll
        for (int j = 0; j < 4; ++j)
#pragma unroll
            for (int p = 0; p < 4; ++p) acc[j][p] = bj[j];
#pragma unroll 4
        for (int i = 0; i < 68; ++i) {
            float4 av = *(const float4*)&act[i * AS + 4 * pgrp];
            float4 wv4 = *(const float4*)&wbuf[i * 64 + 4 * q];
            float a[4] = {av.x, av.y, av.z, av.w};
            float wj[4] = {wv4.x, wv4.y, wv4.z, wv4.w};
#pragma unroll
            for (int j = 0; j < 4; ++j)
#pragma unroll
                for (int p = 0; p < 4; ++p) acc[j][p] = fmaf(a[p], wj[j], acc[j][p]);
        }
#pragma unroll
        for (int j = 0; j < 4; ++j)
#pragma unroll
            for (int p = 0; p < 4; ++p) hres[j][p] = leaky_f(acc[j][p]);
    }
    __syncthreads();

#pragma unroll
    for (int j = 0; j < 4; ++j)
        *(float4*)&act[(4 * q + j) * AS + 4 * pgrp] =
            make_float4(hres[j][0], hres[j][1], hres[j][2], hres[j][3]);
    {
        const float4* wrg = (const float4*)Wr;  // 1024 float4
#pragma unroll
        for (int idx = t; idx < 1024; idx += 256) wbuf4[idx] = wrg[idx];
    }
    __syncthreads();

    // ---- Layer 2 ----
    float h2[4][4];
    {
        float4 b4 = ((const float4*)br)[q];
        float bj[4] = {b4.x, b4.y, b4.z, b4.w};
#pragma unroll
        for (int j = 0; j < 4; ++j)
#pragma unroll
            for (int p = 0; p < 4; ++p) h2[j][p] = bj[j];
#pragma unroll 4
        for (int i = 0; i < 64; ++i) {
            float4 av = *(const float4*)&act[i * AS + 4 * pgrp];
            float4 wv4 = *(const float4*)&wbuf[i * 64 + 4 * q];
            float a[4] = {av.x, av.y, av.z, av.w};
            float wj[4] = {wv4.x, wv4.y, wv4.z, wv4.w};
#pragma unroll
            for (int j = 0; j < 4; ++j)
#pragma unroll
                for (int p = 0; p < 4; ++p) h2[j][p] = fmaf(a[p], wj[j], h2[j][p]);
        }
#pragma unroll
        for (int j = 0; j < 4; ++j)
#pragma unroll
            for (int p = 0; p < 4; ++p) h2[j][p] = leaky_f(hres[j][p] + h2[j][p]);
    }
    __syncthreads();

#pragma unroll
    for (int j = 0; j < 4; ++j)
        *(float4*)&act[(4 * q + j) * AS + 4 * pgrp] =
            make_float4(h2[j][0], h2[j][1], h2[j][2], h2[j][3]);
    {
        const float4* w2g = (const float4*)W2;  // 464 float4
#pragma unroll
        for (int idx = t; idx < 464; idx += 256) wbuf4[idx] = w2g[idx];
    }
    __syncthreads();

    float* sot = wbuf + 2048;  // [64][30] overlay past W2's 1856 floats
    float* prm = wbuf;         // [64][28] overlay on weight region (free after L3)

    // ---- Layer 3 ----
    {
        const int j0 = 2 * q, j1 = 2 * q + 1;
        const int jj0 = min(j0, 28), jj1 = min(j1, 28);
        float o0[4], o1[4];
        float bb0 = b2[jj0], bb1 = b2[jj1];
#pragma unroll
        for (int p = 0; p < 4; ++p) {
            o0[p] = bb0;
            o1[p] = bb1;
        }
#pragma unroll 4
        for (int i = 0; i < 64; ++i) {
            float4 av = *(const float4*)&act[i * AS + 4 * pgrp];
            float a[4] = {av.x, av.y, av.z, av.w};
            float w0 = wbuf[i * 29 + jj0], w1 = wbuf[i * 29 + jj1];
#pragma unroll
            for (int p = 0; p < 4; ++p) {
                o0[p] = fmaf(a[p], w0, o0[p]);
                o1[p] = fmaf(a[p], w1, o1[p]);
            }
        }
#pragma unroll
        for (int p = 0; p < 4; ++p) {
            int pt = 4 * pgrp + p;
            if (j0 < 29) sot[pt * 30 + j0] = o0[p];
            if (j1 < 29) sot[pt * 30 + j1] = o1[p];
        }
    }
    __syncthreads();

    // ---- Head: 4 threads/point; results to prm in LDS ----
    {
        const int pt = t >> 2, sub = t & 3;
        const int pg = blk0 + pt;
        const float* so = sot + pt * 30;
        float gx = coords[2 * pg], gy = coords[2 * pg + 1];
        float r = clampf(softplus_f(so[0]) + 0.1f, 0.1f, 4.0f);
        float sg = clampf(softplus_f(so[1]) + 0.5f, 0.5f, 6.0f);
        float se = sg * 2.0f;
        float inv2 = -0.5f / (se * se + 1e-8f);
        float sx[3], sy[3], wv[3];
        float s = 0.0f;
#pragma unroll
        for (int ii = 0; ii < 3; ++ii) {
            int kr = 4 * ii + sub;
            int k = kr < 9 ? kr : 0;
            float bx = (float)(k % 3 - 1);
            float by = (float)(k / 3 - 1);
            float ox = fmaf(r, bx, tanhf(so[2 + 2 * k]) * 0.5f);
            float oy = fmaf(r, by, tanhf(so[3 + 2 * k]) * 0.5f);
            float d2 = ox * ox + oy * oy;
            float wgeo = expf(d2 * inv2);
            float gate = 1.0f / (1.0f + expf(-so[20 + k]));
            float w = (kr < 9) ? wgeo * gate : 0.0f;
            wv[ii] = w;
            s += w;
            sx[ii] = fmaf(ox, SCLX, gx);
            sy[ii] = fmaf(oy, SCLY, gy);
        }
        s += __shfl_xor(s, 1, 64);
        s += __shfl_xor(s, 2, 64);
        float inv = 1.0f / (s + 1e-8f);
        float* pp = prm + pt * 28;
#pragma unroll
        for (int ii = 0; ii < 3; ++ii) {
            int kr = 4 * ii + sub;
            if (kr < 9) {
                pp[3 * kr + 0] = sx[ii];
                pp[3 * kr + 1] = sy[ii];
                pp[3 * kr + 2] = wv[ii] * inv;
            }
        }
    }
    __syncthreads();

    // ---- Gather: 4 (pt,c4) tasks/thread, 9 taps each ----
#pragma unroll
    for (int g = 0; g < 4; ++g) {
        int task = g * 256 + t;
        int c4 = task & 15;
        int pt = task >> 4;
        int pg = blk0 + pt;
        int bb = pg >> 14;
        const unsigned short* base = featB + (size_t)bb * (HH * WW) * 64;
        const float* pp = prm + pt * 28;
        float4 acc = make_float4(0.0f, 0.0f, 0.0f, 0.0f);
#pragma unroll 3
        for (int k = 0; k < K_TAPS; ++k) {
            float sx = pp[3 * k + 0];
            float sy = pp[3 * k + 1];
            float wk = pp[3 * k + 2];
            float4 v = bilin4_bf(base, sx, sy, c4);
            acc.x = fmaf(v.x, wk, acc.x);
            acc.y = fmaf(v.y, wk, acc.y);
            acc.z = fmaf(v.z, wk, acc.z);
            acc.w = fmaf(v.w, wk, acc.w);
        }
        out4[(size_t)pg * 16 + c4] = acc;
    }
}

// ---------------- small fallback: CHW fp32, wave per point (no workspace) ----------------
__device__ __forceinline__ float bilin_chw(const float* __restrict__ feat, int b, int lane,
                                           float gx, float gy) {
    float ix = clampf((gx + 1.0f) * 0.5f * 255.0f, 0.0f, 255.0f);
    float iy = clampf((gy + 1.0f) * 0.5f * 255.0f, 0.0f, 255.0f);
    float x0f = floorf(ix), y0f = floorf(iy);
    float wx = ix - x0f, wy = iy - y0f;
    int x0 = (int)x0f, y0 = (int)y0f;
    int x1 = min(x0 + 1, 255), y1 = min(y0 + 1, 255);
    const float* base = feat + ((size_t)b * CC + lane) * (HH * WW);
    float f00 = base[(y0 << 8) + x0];
    float f01 = base[(y0 << 8) + x1];
    float f10 = base[(y1 << 8) + x0];
    float f11 = base[(y1 << 8) + x1];
    float omx = 1.0f - wx, omy = 1.0f - wy;
    return (f00 * omx + f01 * wx) * omy + (f10 * omx + f11 * wx) * wy;
}

__global__ void __launch_bounds__(256) fallback_kernel(const float* __restrict__ feat,
                                                       const float* __restrict__ coords,
                                                       const float* __restrict__ cell,
                                                       const float* __restrict__ W1,
                                                       const float* __restrict__ b1,
                                                       const float* __restrict__ Wr,
                                                       const float* __restrict__ br,
                                                       const float* __restrict__ W2,
                                                       const float* __restrict__ b2,
                                                       float* __restrict__ out) {
    int lane = threadIdx.x & 63;
    int wave = threadIdx.x >> 6;
    int pidx = blockIdx.x * 4 + wave;
    if (pidx >= NPTS) return;
    int b = pidx >> 14;
    float gx = coords[(size_t)pidx * 2 + 0];
    float gy = coords[(size_t)pidx * 2 + 1];
    float cx = cell[(size_t)pidx * 2 + 0];
    float cy = cell[(size_t)pidx * 2 + 1];
    float fa = bilin_chw(feat, b, lane, gx, gy);
    float h = b1[lane];
#pragma unroll
    for (int i = 0; i < 64; ++i) {
        float a = __shfl(fa, i, 64);
        h = fmaf(a, W1[i * 64 + lane], h);
    }
    h = fmaf(gx, W1[64 * 64 + lane], h);
    h = fmaf(gy, W1[65 * 64 + lane], h);
    h = fmaf(cx, W1[66 * 64 + lane], h);
    h = fmaf(cy, W1[67 * 64 + lane], h);
    h = leaky_f(h);
    float h2 = br[lane];
#pragma unroll
    for (int i = 0; i < 64; ++i) {
        float a = __shfl(h, i, 64);
        h2 = fmaf(a, Wr[i * 64 + lane], h2);
    }
    h2 = leaky_f(h + h2);
    int j = lane < 29 ? lane : 0;
    float o = b2[j];
#pragma unroll
    for (int i = 0; i < 64; ++i) {
        float a = __shfl(h2, i, 64);
        o = fmaf(a, W2[i * 29 + j], o);
    }
    int kk = lane < K_TAPS ? lane : 0;
    float r_raw = __shfl(o, 0, 64);
    float s_raw = __shfl(o, 1, 64);
    float rx_raw = __shfl(o, 2 + 2 * kk, 64);
    float ry_raw = __shfl(o, 3 + 2 * kk, 64);
    float g_raw = __shfl(o, 20 + kk, 64);
    float r = clampf(softplus_f(r_raw) + 0.1f, 0.1f, 4.0f);
    float sg = clampf(softplus_f(s_raw) + 0.5f, 0.5f, 6.0f);
    float bx = (float)(kk % 3 - 1);
    float by = (float)(kk / 3 - 1);
    float offx = fmaf(r, bx, tanhf(rx_raw) * 0.5f);
    float offy = fmaf(r, by, tanhf(ry_raw) * 0.5f);
    float d2 = offx * offx + offy * offy;
    float se = sg * 2.0f;
    float wgeo = expf(-0.5f * d2 / (se * se + 1e-8f));
    float gate = 1.0f / (1.0f + expf(-g_raw));
    float w = wgeo * gate;
    float wv = (lane < K_TAPS) ? w : 0.0f;
#pragma unroll
    for (int m = 32; m >= 1; m >>= 1) wv += __shfl_xor(wv, m, 64);
    float wn = w / (wv + 1e-8f);
    float acc = 0.0f;
#pragma unroll
    for (int k = 0; k < K_TAPS; ++k) {
        float ox = __shfl(offx, k, 64) * SCLX;
        float oy = __shfl(offy, k, 64) * SCLY;
        float wk2 = __shfl(wn, k, 64);
        float fv = bilin_chw(feat, b, lane, gx + ox, gy + oy);
        acc = fmaf(fv, wk2, acc);
    }
    out[(size_t)pidx * CC + lane] = acc;
}

extern "C" void kernel_launch(void* const* d_in, const int* in_sizes, int n_in,
                              void* d_out, int out_size, void* d_ws, size_t ws_size,
                              hipStream_t stream) {
    const float* feat = (const float*)d_in[0];
    const float* coords = (const float*)d_in[1];
    const float* cell = (const float*)d_in[2];
    const float* W1 = (const float*)d_in[3];
    const float* b1 = (const float*)d_in[4];
    const float* Wr = (const float*)d_in[5];
    const float* br = (const float*)d_in[6];
    const float* W2 = (const float*)d_in[7];
    const float* b2 = (const float*)d_in[8];
    float* out = (float*)d_out;

    const size_t needT = (size_t)BB * HH * WW * CC * sizeof(unsigned short);  // 32 MB

    if (ws_size >= needT) {
        unsigned short* featB = (unsigned short*)d_ws;
        dim3 tg((HH * WW) / 64, BB);
        transpose_kernel<<<tg, 256, 0, stream>>>(feat, (unsigned int*)featB);
        fused_kernel<<<NPTS / 64, 256, 0, stream>>>(featB, coords, cell, W1, b1, Wr, br, W2,
                                                    b2, (float4*)out);
    } else {
        fallback_kernel<<<NPTS / 4, 256, 0, stream>>>(feat, coords, cell, W1, b1, Wr, br, W2,
                                                      b2, out);
    }
}

// Round 12
// 72.921 us; speedup vs baseline: 2.6372x; 1.0098x over previous
//
#include <hip/hip_runtime.h>

#define K_TAPS 9
#define CC 64
#define HH 256
#define WW 256
#define BB 4
#define NN 16384
#define NPTS (BB * NN)
#define SCLX (2.0f / 255.0f)
#define SCLY (2.0f / 255.0f)
#define AS 68  // act row stride (floats)

__device__ __forceinline__ float softplus_f(float x) {
    return fmaxf(x, 0.0f) + log1pf(expf(-fabsf(x)));
}
__device__ __forceinline__ float leaky_f(float x) { return x >= 0.0f ? x : 0.2f * x; }
__device__ __forceinline__ float clampf(float x, float lo, float hi) {
    return fminf(fmaxf(x, lo), hi);
}
__device__ __forceinline__ float bf2f(unsigned short u) {
    union { unsigned int i; float f; } v;
    v.i = (unsigned int)u << 16;
    return v.f;
}
__device__ __forceinline__ unsigned short f2bf(float f) {
    union { float f; unsigned int i; } v;
    v.f = f;
    unsigned int r = (v.i + 0x7FFFu + ((v.i >> 16) & 1u)) >> 16;
    return (unsigned short)r;
}

// transpose (B, C, H*W) fp32 -> (B, H*W, C) bf16
__global__ void __launch_bounds__(256) transpose_kernel(const float* __restrict__ feat,
                                                        unsigned int* __restrict__ featB) {
    __shared__ float tile[64][65];
    int b = blockIdx.y;
    int p0 = blockIdx.x * 64;
    int tp = threadIdx.x & 63;
    int tq = threadIdx.x >> 6;
    const float* fb = feat + (size_t)b * CC * HH * WW;
#pragma unroll
    for (int i = 0; i < 16; ++i) {
        int c = tq * 16 + i;
        tile[c][tp] = fb[(size_t)c * (HH * WW) + p0 + tp];
    }
    __syncthreads();
    unsigned int* ob = featB + ((size_t)b * (HH * WW) + p0) * 32;
    int c2 = threadIdx.x & 31;
    int psub = threadIdx.x >> 5;
#pragma unroll
    for (int i = 0; i < 8; ++i) {
        int p = i * 8 + psub;
        unsigned int lo = f2bf(tile[2 * c2][p]);
        unsigned int hi = f2bf(tile[2 * c2 + 1][p]);
        ob[(size_t)p * 32 + c2] = lo | (hi << 16);
    }
}

// bilinear sample of 4 bf16 channels at grid coords (gx,gy); c4 = channel quad
__device__ __forceinline__ float4 bilin4_bf(const unsigned short* __restrict__ base, float gx,
                                            float gy, int c4) {
    float ix = clampf((gx + 1.0f) * 0.5f * 255.0f, 0.0f, 255.0f);
    float iy = clampf((gy + 1.0f) * 0.5f * 255.0f, 0.0f, 255.0f);
    float x0f = floorf(ix), y0f = floorf(iy);
    float wx = ix - x0f, wy = iy - y0f;
    int x0 = (int)x0f, y0 = (int)y0f;
    int x1 = min(x0 + 1, 255), y1 = min(y0 + 1, 255);
    const ushort4 u00 = *(const ushort4*)(base + (size_t)(((y0 << 8) + x0) * 64) + c4 * 4);
    const ushort4 u01 = *(const ushort4*)(base + (size_t)(((y0 << 8) + x1) * 64) + c4 * 4);
    const ushort4 u10 = *(const ushort4*)(base + (size_t)(((y1 << 8) + x0) * 64) + c4 * 4);
    const ushort4 u11 = *(const ushort4*)(base + (size_t)(((y1 << 8) + x1) * 64) + c4 * 4);
    float w00 = (1.0f - wx) * (1.0f - wy), w01 = wx * (1.0f - wy);
    float w10 = (1.0f - wx) * wy, w11 = wx * wy;
    float4 v;
    v.x = bf2f(u00.x) * w00 + bf2f(u01.x) * w01 + bf2f(u10.x) * w10 + bf2f(u11.x) * w11;
    v.y = bf2f(u00.y) * w00 + bf2f(u01.y) * w01 + bf2f(u10.y) * w10 + bf2f(u11.y) * w11;
    v.z = bf2f(u00.z) * w00 + bf2f(u01.z) * w01 + bf2f(u10.z) * w10 + bf2f(u11.z) * w11;
    v.w = bf2f(u00.w) * w00 + bf2f(u01.w) * w01 + bf2f(u10.w) * w10 + bf2f(u11.w) * w11;
    return v;
}

// ---------------- fused: anchor + MLP + head + deformable gather; 64 points/block ----------
// Round-9 structure (known-good) + T14 async-stage of Wr/W2 weight prefetch.
__global__ void __launch_bounds__(256, 4) fused_kernel(const unsigned short* __restrict__ featB,
                                                       const float* __restrict__ coords,
                                                       const float* __restrict__ cell,
                                                       const float* __restrict__ W1,
                                                       const float* __restrict__ b1,
                                                       const float* __restrict__ Wr,
                                                       const float* __restrict__ br,
                                                       const float* __restrict__ W2,
                                                       const float* __restrict__ b2,
                                                       float4* __restrict__ out4) {
    __shared__ __align__(16) float act[68 * AS];   // [feature i][point 0..63]
    __shared__ __align__(16) float wbuf[68 * 64];  // W1 -> Wr -> (W2 | sot) -> (prm | sot)
    float4* wbuf4 = (float4*)wbuf;

    const int t = threadIdx.x;
    const int q = t & 15;
    const int pgrp = t >> 4;
    const int blk0 = blockIdx.x * 64;

    // ---- Phase A: issue W1 staging loads, then anchor corner loads, then LDS writes ----
    {
        const int pt = t & 63;
        const int wvi = t >> 6;
        const int pg = blk0 + pt;
        const int bb2 = pg >> 14;
        const float gx = coords[2 * pg], gy = coords[2 * pg + 1];

        // W1 staging loads (1088 float4): 4 full rounds + partial (t<64)
        const float4* w1g = (const float4*)W1;
        float4 w1r0 = w1g[t];
        float4 w1r1 = w1g[t + 256];
        float4 w1r2 = w1g[t + 512];
        float4 w1r3 = w1g[t + 768];
        float4 w1x;
        if (t < 64) w1x = w1g[1024 + t];

        // anchor corner loads
        float ix = clampf((gx + 1.0f) * 0.5f * 255.0f, 0.0f, 255.0f);
        float iy = clampf((gy + 1.0f) * 0.5f * 255.0f, 0.0f, 255.0f);
        float x0f = floorf(ix), y0f = floorf(iy);
        float wx = ix - x0f, wy = iy - y0f;
        int x0 = (int)x0f, y0 = (int)y0f;
        int x1 = min(x0 + 1, 255), y1 = min(y0 + 1, 255);
        const unsigned short* base = featB + (size_t)bb2 * (HH * WW) * 64;
        size_t i00 = (size_t)(((y0 << 8) + x0) * 64), i01 = (size_t)(((y0 << 8) + x1) * 64);
        size_t i10 = (size_t)(((y1 << 8) + x0) * 64), i11 = (size_t)(((y1 << 8) + x1) * 64);
        ushort4 u00[4], u01[4], u10[4], u11[4];
#pragma unroll
        for (int g = 0; g < 4; ++g) {
            int qq = 4 * g + wvi;
            u00[g] = *(const ushort4*)(base + i00 + qq * 4);
            u01[g] = *(const ushort4*)(base + i01 + qq * 4);
            u10[g] = *(const ushort4*)(base + i10 + qq * 4);
            u11[g] = *(const ushort4*)(base + i11 + qq * 4);
        }

        // W1 -> LDS
        wbuf4[t] = w1r0;
        wbuf4[t + 256] = w1r1;
        wbuf4[t + 512] = w1r2;
        wbuf4[t + 768] = w1r3;
        if (t < 64) wbuf4[1024 + t] = w1x;

        // combine corners -> act
        float w00 = (1.0f - wx) * (1.0f - wy), w01 = wx * (1.0f - wy);
        float w10 = (1.0f - wx) * wy, w11 = wx * wy;
#pragma unroll
        for (int g = 0; g < 4; ++g) {
            int qq = 4 * g + wvi;
            act[(4 * qq + 0) * AS + pt] = bf2f(u00[g].x) * w00 + bf2f(u01[g].x) * w01 +
                                          bf2f(u10[g].x) * w10 + bf2f(u11[g].x) * w11;
            act[(4 * qq + 1) * AS + pt] = bf2f(u00[g].y) * w00 + bf2f(u01[g].y) * w01 +
                                          bf2f(u10[g].y) * w10 + bf2f(u11[g].y) * w11;
            act[(4 * qq + 2) * AS + pt] = bf2f(u00[g].z) * w00 + bf2f(u01[g].z) * w01 +
                                          bf2f(u10[g].z) * w10 + bf2f(u11[g].z) * w11;
            act[(4 * qq + 3) * AS + pt] = bf2f(u00[g].w) * w00 + bf2f(u01[g].w) * w01 +
                                          bf2f(u10[g].w) * w10 + bf2f(u11[g].w) * w11;
        }
        if (wvi == 0) {
            act[64 * AS + pt] = gx;
            act[65 * AS + pt] = gy;
            act[66 * AS + pt] = cell[2 * pg];
            act[67 * AS + pt] = cell[2 * pg + 1];
        }
    }
    __syncthreads();

    // ---- T14: prefetch Wr into registers; latency hides under Layer-1 compute ----
    const float4* wrg = (const float4*)Wr;  // 1024 float4, 4 per thread
    float4 wrp0 = wrg[t];
    float4 wrp1 = wrg[t + 256];
    float4 wrp2 = wrg[t + 512];
    float4 wrp3 = wrg[t + 768];

    // ---- Layer 1 ----
    float hres[4][4];
    {
        float acc[4][4];
        float4 b4 = ((const float4*)b1)[q];
        float bj[4] = {b4.x, b4.y, b4.z, b4.w};
#pragma unroll
        for (int j = 0; j < 4; ++j)
#pragma unroll
            for (int p = 0; p < 4; ++p) acc[j][p] = bj[j];
#pragma unroll 4
        for (int i = 0; i < 68; ++i) {
            float4 av = *(const float4*)&act[i * AS + 4 * pgrp];
            float4 wv4 = *(const float4*)&wbuf[i * 64 + 4 * q];
            float a[4] = {av.x, av.y, av.z, av.w};
            float wj[4] = {wv4.x, wv4.y, wv4.z, wv4.w};
#pragma unroll
            for (int j = 0; j < 4; ++j)
#pragma unroll
                for (int p = 0; p < 4; ++p) acc[j][p] = fmaf(a[p], wj[j], acc[j][p]);
        }
#pragma unroll
        for (int j = 0; j < 4; ++j)
#pragma unroll
            for (int p = 0; p < 4; ++p) hres[j][p] = leaky_f(acc[j][p]);
    }
    __syncthreads();  // layer-1 act & wbuf reads complete

    // write h into act rows; commit prefetched Wr to LDS
#pragma unroll
    for (int j = 0; j < 4; ++j)
        *(float4*)&act[(4 * q + j) * AS + 4 * pgrp] =
            make_float4(hres[j][0], hres[j][1], hres[j][2], hres[j][3]);
    wbuf4[t] = wrp0;
    wbuf4[t + 256] = wrp1;
    wbuf4[t + 512] = wrp2;
    wbuf4[t + 768] = wrp3;
    __syncthreads();

    // ---- T14: prefetch W2 (464 float4) into registers; hides under Layer-2 compute ----
    const float4* w2g = (const float4*)W2;
    float4 w2p0, w2p1;
    if (t < 232) {
        w2p0 = w2g[t];
        w2p1 = w2g[t + 232];
    }

    // ---- Layer 2 ----
    float h2[4][4];
    {
        float4 b4 = ((const float4*)br)[q];
        float bj[4] = {b4.x, b4.y, b4.z, b4.w};
#pragma unroll
        for (int j = 0; j < 4; ++j)
#pragma unroll
            for (int p = 0; p < 4; ++p) h2[j][p] = bj[j];
#pragma unroll 4
        for (int i = 0; i < 64; ++i) {
            float4 av = *(const float4*)&act[i * AS + 4 * pgrp];
            float4 wv4 = *(const float4*)&wbuf[i * 64 + 4 * q];
            float a[4] = {av.x, av.y, av.z, av.w};
            float wj[4] = {wv4.x, wv4.y, wv4.z, wv4.w};
#pragma unroll
            for (int j = 0; j < 4; ++j)
#pragma unroll
                for (int p = 0; p < 4; ++p) h2[j][p] = fmaf(a[p], wj[j], h2[j][p]);
        }
#pragma unroll
        for (int j = 0; j < 4; ++j)
#pragma unroll
            for (int p = 0; p < 4; ++p) h2[j][p] = leaky_f(hres[j][p] + h2[j][p]);
    }
    __syncthreads();  // layer-2 reads complete

    // write h2 into act rows; commit prefetched W2 to LDS
#pragma unroll
    for (int j = 0; j < 4; ++j)
        *(float4*)&act[(4 * q + j) * AS + 4 * pgrp] =
            make_float4(h2[j][0], h2[j][1], h2[j][2], h2[j][3]);
    if (t < 232) {
        wbuf4[t] = w2p0;
        wbuf4[t + 232] = w2p1;
    }
    __syncthreads();

    float* sot = wbuf + 2048;  // [64][30] overlay past W2's 1856 floats
    float* prm = wbuf;         // [64][28] overlay on weight region (free after L3)

    // ---- Layer 3 ----
    {
        const int j0 = 2 * q, j1 = 2 * q + 1;
        const int jj0 = min(j0, 28), jj1 = min(j1, 28);
        float o0[4], o1[4];
        float bb0 = b2[jj0], bb1 = b2[jj1];
#pragma unroll
        for (int p = 0; p < 4; ++p) {
            o0[p] = bb0;
            o1[p] = bb1;
        }
#pragma unroll 4
        for (int i = 0; i < 64; ++i) {
            float4 av = *(const float4*)&act[i * AS + 4 * pgrp];
            float a[4] = {av.x, av.y, av.z, av.w};
            float w0 = wbuf[i * 29 + jj0], w1 = wbuf[i * 29 + jj1];
#pragma unroll
            for (int p = 0; p < 4; ++p) {
                o0[p] = fmaf(a[p], w0, o0[p]);
                o1[p] = fmaf(a[p], w1, o1[p]);
            }
        }
#pragma unroll
        for (int p = 0; p < 4; ++p) {
            int pt = 4 * pgrp + p;
            if (j0 < 29) sot[pt * 30 + j0] = o0[p];
            if (j1 < 29) sot[pt * 30 + j1] = o1[p];
        }
    }
    __syncthreads();

    // ---- Head: 4 threads/point; results to prm in LDS ----
    {
        const int pt = t >> 2, sub = t & 3;
        const int pg = blk0 + pt;
        const float* so = sot + pt * 30;
        float gx = coords[2 * pg], gy = coords[2 * pg + 1];
        float r = clampf(softplus_f(so[0]) + 0.1f, 0.1f, 4.0f);
        float sg = clampf(softplus_f(so[1]) + 0.5f, 0.5f, 6.0f);
        float se = sg * 2.0f;
        float inv2 = -0.5f / (se * se + 1e-8f);
        float sx[3], sy[3], wv[3];
        float s = 0.0f;
#pragma unroll
        for (int ii = 0; ii < 3; ++ii) {
            int kr = 4 * ii + sub;
            int k = kr < 9 ? kr : 0;
            float bx = (float)(k % 3 - 1);
            float by = (float)(k / 3 - 1);
            float ox = fmaf(r, bx, tanhf(so[2 + 2 * k]) * 0.5f);
            float oy = fmaf(r, by, tanhf(so[3 + 2 * k]) * 0.5f);
            float d2 = ox * ox + oy * oy;
            float wgeo = expf(d2 * inv2);
            float gate = 1.0f / (1.0f + expf(-so[20 + k]));
            float w = (kr < 9) ? wgeo * gate : 0.0f;
            wv[ii] = w;
            s += w;
            sx[ii] = fmaf(ox, SCLX, gx);
            sy[ii] = fmaf(oy, SCLY, gy);
        }
        s += __shfl_xor(s, 1, 64);
        s += __shfl_xor(s, 2, 64);
        float inv = 1.0f / (s + 1e-8f);
        float* pp = prm + pt * 28;
#pragma unroll
        for (int ii = 0; ii < 3; ++ii) {
            int kr = 4 * ii + sub;
            if (kr < 9) {
                pp[3 * kr + 0] = sx[ii];
                pp[3 * kr + 1] = sy[ii];
                pp[3 * kr + 2] = wv[ii] * inv;
            }
        }
    }
    __syncthreads();

    // ---- Gather: 4 (pt,c4) tasks/thread, 9 taps each ----
#pragma unroll
    for (int g2 = 0; g2 < 4; ++g2) {
        int task = g2 * 256 + t;
        int c4 = task & 15;
        int pt = task >> 4;
        int pg = blk0 + pt;
        int bb2 = pg >> 14;
        const unsigned short* base = featB + (size_t)bb2 * (HH * WW) * 64;
        const float* pp = prm + pt * 28;
        float4 acc = make_float4(0.0f, 0.0f, 0.0f, 0.0f);
#pragma unroll 3
        for (int k = 0; k < K_TAPS; ++k) {
            float sx = pp[3 * k + 0];
            float sy = pp[3 * k + 1];
            float wk = pp[3 * k + 2];
            float4 v = bilin4_bf(base, sx, sy, c4);
            acc.x = fmaf(v.x, wk, acc.x);
            acc.y = fmaf(v.y, wk, acc.y);
            acc.z = fmaf(v.z, wk, acc.z);
            acc.w = fmaf(v.w, wk, acc.w);
        }
        out4[(size_t)pg * 16 + c4] = acc;
    }
}

// ---------------- small fallback: CHW fp32, wave per point (no workspace) ----------------
__device__ __forceinline__ float bilin_chw(const float* __restrict__ feat, int b, int lane,
                                           float gx, float gy) {
    float ix = clampf((gx + 1.0f) * 0.5f * 255.0f, 0.0f, 255.0f);
    float iy = clampf((gy + 1.0f) * 0.5f * 255.0f, 0.0f, 255.0f);
    float x0f = floorf(ix), y0f = floorf(iy);
    float wx = ix - x0f, wy = iy - y0f;
    int x0 = (int)x0f, y0 = (int)y0f;
    int x1 = min(x0 + 1, 255), y1 = min(y0 + 1, 255);
    const float* base = feat + ((size_t)b * CC + lane) * (HH * WW);
    float f00 = base[(y0 << 8) + x0];
    float f01 = base[(y0 << 8) + x1];
    float f10 = base[(y1 << 8) + x0];
    float f11 = base[(y1 << 8) + x1];
    float omx = 1.0f - wx, omy = 1.0f - wy;
    return (f00 * omx + f01 * wx) * omy + (f10 * omx + f11 * wx) * wy;
}

__global__ void __launch_bounds__(256) fallback_kernel(const float* __restrict__ feat,
                                                       const float* __restrict__ coords,
                                                       const float* __restrict__ cell,
                                                       const float* __restrict__ W1,
                                                       const float* __restrict__ b1,
                                                       const float* __restrict__ Wr,
                                                       const float* __restrict__ br,
                                                       const float* __restrict__ W2,
                                                       const float* __restrict__ b2,
                                                       float* __restrict__ out) {
    int lane = threadIdx.x & 63;
    int wave = threadIdx.x >> 6;
    int pidx = blockIdx.x * 4 + wave;
    if (pidx >= NPTS) return;
    int b = pidx >> 14;
    float gx = coords[(size_t)pidx * 2 + 0];
    float gy = coords[(size_t)pidx * 2 + 1];
    float cx = cell[(size_t)pidx * 2 + 0];
    float cy = cell[(size_t)pidx * 2 + 1];
    float fa = bilin_chw(feat, b, lane, gx, gy);
    float h = b1[lane];
#pragma unroll
    for (int i = 0; i < 64; ++i) {
        float a = __shfl(fa, i, 64);
        h = fmaf(a, W1[i * 64 + lane], h);
    }
    h = fmaf(gx, W1[64 * 64 + lane], h);
    h = fmaf(gy, W1[65 * 64 + lane], h);
    h = fmaf(cx, W1[66 * 64 + lane], h);
    h = fmaf(cy, W1[67 * 64 + lane], h);
    h = leaky_f(h);
    float h2 = br[lane];
#pragma unroll
    for (int i = 0; i < 64; ++i) {
        float a = __shfl(h, i, 64);
        h2 = fmaf(a, Wr[i * 64 + lane], h2);
    }
    h2 = leaky_f(h + h2);
    int j = lane < 29 ? lane : 0;
    float o = b2[j];
#pragma unroll
    for (int i = 0; i < 64; ++i) {
        float a = __shfl(h2, i, 64);
        o = fmaf(a, W2[i * 29 + j], o);
    }
    int kk = lane < K_TAPS ? lane : 0;
    float r_raw = __shfl(o, 0, 64);
    float s_raw = __shfl(o, 1, 64);
    float rx_raw = __shfl(o, 2 + 2 * kk, 64);
    float ry_raw = __shfl(o, 3 + 2 * kk, 64);
    float g_raw = __shfl(o, 20 + kk, 64);
    float r = clampf(softplus_f(r_raw) + 0.1f, 0.1f, 4.0f);
    float sg = clampf(softplus_f(s_raw) + 0.5f, 0.5f, 6.0f);
    float bx = (float)(kk % 3 - 1);
    float by = (float)(kk / 3 - 1);
    float offx = fmaf(r, bx, tanhf(rx_raw) * 0.5f);
    float offy = fmaf(r, by, tanhf(ry_raw) * 0.5f);
    float d2 = offx * offx + offy * offy;
    float se = sg * 2.0f;
    float wgeo = expf(-0.5f * d2 / (se * se + 1e-8f));
    float gate = 1.0f / (1.0f + expf(-g_raw));
    float w = wgeo * gate;
    float wv = (lane < K_TAPS) ? w : 0.0f;
#pragma unroll
    for (int m = 32; m >= 1; m >>= 1) wv += __shfl_xor(wv, m, 64);
    float wn = w / (wv + 1e-8f);
    float acc = 0.0f;
#pragma unroll
    for (int k = 0; k < K_TAPS; ++k) {
        float ox = __shfl(offx, k, 64) * SCLX;
        float oy = __shfl(offy, k, 64) * SCLY;
        float wk2 = __shfl(wn, k, 64);
        float fv = bilin_chw(feat, b, lane, gx + ox, gy + oy);
        acc = fmaf(fv, wk2, acc);
    }
    out[(size_t)pidx * CC + lane] = acc;
}

extern "C" void kernel_launch(void* const* d_in, const int* in_sizes, int n_in,
                              void* d_out, int out_size, void* d_ws, size_t ws_size,
                              hipStream_t stream) {
    const float* feat = (const float*)d_in[0];
    const float* coords = (const float*)d_in[1];
    const float* cell = (const float*)d_in[2];
    const float* W1 = (const float*)d_in[3];
    const float* b1 = (const float*)d_in[4];
    const float* Wr = (const float*)d_in[5];
    const float* br = (const float*)d_in[6];
    const float* W2 = (const float*)d_in[7];
    const float* b2 = (const float*)d_in[8];
    float* out = (float*)d_out;

    const size_t needT = (size_t)BB * HH * WW * CC * sizeof(unsigned short);  // 32 MB

    if (ws_size >= needT) {
        unsigned short* featB = (unsigned short*)d_ws;
        dim3 tg((HH * WW) / 64, BB);
        transpose_kernel<<<tg, 256, 0, stream>>>(feat, (unsigned int*)featB);
        fused_kernel<<<NPTS / 64, 256, 0, stream>>>(featB, coords, cell, W1, b1, Wr, br, W2,
                                                    b2, (float4*)out);
    } else {
        fallback_kernel<<<NPTS / 4, 256, 0, stream>>>(feat, coords, cell, W1, b1, Wr, br, W2,
                                                      b2, out);
    }
}